// Round 13
// baseline (132.082 us; speedup 1.0000x reference)
//
#include <hip/hip_runtime.h>
#include <hip/hip_bf16.h>

typedef __attribute__((ext_vector_type(8))) short short8;
typedef __attribute__((ext_vector_type(4))) float f32x4;

__device__ inline short f2bf(float x) {
    union { __hip_bfloat16 b; short s; } u;
    u.b = __float2bfloat16(x);
    return u.s;
}
__device__ inline float bf2f(short s) {
    union { __hip_bfloat16 b; short s; } u;
    u.s = s;
    return __bfloat162float(u.b);
}

#define GLDS16(g, l) __builtin_amdgcn_global_load_lds( \
    (const __attribute__((address_space(1))) void*)(g), \
    (__attribute__((address_space(3))) void*)(l), 16, 0, 0)

// ------- transpose v2: 64x64 tiles, float4 loads, short8 writes (128B segments) -------
__global__ __launch_bounds__(256) void transpose_v2(const float* __restrict__ W1,
                                                    const float* __restrict__ features,
                                                    const float* __restrict__ W2,
                                                    const float* __restrict__ Wc,
                                                    const float* __restrict__ Wb,
                                                    short* __restrict__ W1t,
                                                    short* __restrict__ featT,
                                                    short* __restrict__ W2t,
                                                    short* __restrict__ Wht) {
    __shared__ float tile[64][65];
    int id = blockIdx.x;
    const float* in;
    short* out;
    int R, C, r0, c0;
    if (id < 3136) {
        in = W1; out = W1t; R = 12544; C = 1024;
        r0 = (id % 196) * 64; c0 = (id / 196) * 64;
    } else if (id < 3456) {
        int f = id - 3136;
        int img = f / 160, g = f % 160;
        in = features + (long)img * 640000;
        out = featT + (long)img * 640000;
        R = 256; C = 2500;
        r0 = (g % 4) * 64; c0 = (g / 4) * 64;
    } else if (id < 3712) {
        int g = id - 3456;
        in = W2; out = W2t; R = 1024; C = 1024;
        r0 = (g % 16) * 64; c0 = (g / 16) * 64;
    } else if (id < 3744) {
        int g = id - 3712;
        in = Wc; out = Wht; R = 1024; C = 81;
        r0 = (g % 16) * 64; c0 = (g / 16) * 64;
    } else {
        int g = id - 3744;
        in = Wb; out = Wht + 81 * 1024; R = 1024; C = 324;
        r0 = (g % 16) * 64; c0 = (g / 16) * 64;
    }
    int tid = threadIdx.x;
    int tr = tid >> 4, tc = tid & 15;
    if (c0 + 64 <= C) {
        #pragma unroll
        for (int i = 0; i < 4; ++i) {
            int r = r0 + tr + i * 16;
            float4 v = *(const float4*)(in + (long)r * C + c0 + tc * 4);
            tile[tr + i * 16][tc * 4 + 0] = v.x;
            tile[tr + i * 16][tc * 4 + 1] = v.y;
            tile[tr + i * 16][tc * 4 + 2] = v.z;
            tile[tr + i * 16][tc * 4 + 3] = v.w;
        }
    } else {
        #pragma unroll
        for (int i = 0; i < 4; ++i) {
            int r = r0 + tr + i * 16;
            #pragma unroll
            for (int e = 0; e < 4; ++e) {
                int c = c0 + tc * 4 + e;
                tile[tr + i * 16][tc * 4 + e] = (c < C) ? in[(long)r * C + c] : 0.f;
            }
        }
    }
    __syncthreads();
    #pragma unroll
    for (int p = 0; p < 2; ++p) {
        int n = (tid >> 3) + p * 32;
        int k0 = (tid & 7) * 8;
        if (c0 + n < C) {
            short8 o;
            #pragma unroll
            for (int j = 0; j < 8; ++j) o[j] = f2bf(tile[k0 + j][n]);
            *(short8*)(out + (long)(c0 + n) * R + r0 + k0) = o;
        }
    }
}

// ---------------- ROI-align v3: 16B vector loads, wave-half corner split ----------
__global__ __launch_bounds__(256) void roi_align_v3(const short* __restrict__ featT,
                                                    const float* __restrict__ props,
                                                    short* __restrict__ Xb) {
    int roi = blockIdx.x;
    int img = roi >> 9;
    __shared__ unsigned int soffB[784];
    __shared__ float swB[784];
    __shared__ float pbox[4];
    __shared__ short outb[49 * 264];
    int tid = threadIdx.x;
    if (tid < 4) pbox[tid] = props[roi * 4 + tid];
    __syncthreads();
    if (tid < 196) {
        float x1 = pbox[0] * 0.0625f, y1 = pbox[1] * 0.0625f;
        float x2 = pbox[2] * 0.0625f, y2 = pbox[3] * 0.0625f;
        float rw = fmaxf(x2 - x1, 1.0f), rh = fmaxf(y2 - y1, 1.0f);
        int p = tid >> 2, q = tid & 3;
        int py = p / 7, px = p % 7;
        int sy = q >> 1, sx = q & 1;
        int gy = py * 2 + sy, gx = px * 2 + sx;
        float gyv = ((float)gy + 0.5f) * 0.5f;
        float gxv = ((float)gx + 0.5f) * 0.5f;
        float ys = y1 + gyv * (rh * (1.0f / 7.0f));
        float xs = x1 + gxv * (rw * (1.0f / 7.0f));
        ys = fminf(fmaxf(ys, 0.0f), 49.0f);
        xs = fminf(fmaxf(xs, 0.0f), 49.0f);
        float y0f = floorf(ys), x0f = floorf(xs);
        int y0 = (int)y0f, x0 = (int)x0f;
        int y1i = min(y0 + 1, 49), x1i = min(x0 + 1, 49);
        float ly = ys - y0f, lx = xs - x0f;
        float hy = 1.f - ly, hx = 1.f - lx;
        int b00 = (y0 * 50 + x0) << 9;
        int ddx = (x1i - x0) << 9;
        int ddy = (y1i - y0) * 25600;
        int t4 = tid << 2;
        soffB[t4 + 0] = b00;             swB[t4 + 0] = hy * hx * 0.25f;
        soffB[t4 + 1] = b00 + ddx;       swB[t4 + 1] = hy * lx * 0.25f;
        soffB[t4 + 2] = b00 + ddy;       swB[t4 + 2] = ly * hx * 0.25f;
        soffB[t4 + 3] = b00 + ddy + ddx; swB[t4 + 3] = ly * lx * 0.25f;
    }
    __syncthreads();
    int w = tid >> 6, l = tid & 63;
    int half = l >> 5, ch16 = l & 31;
    const char* fbase = (const char*)featT + (long)img * 1280000 + (ch16 << 4);
    for (int p = w; p < 49; p += 4) {
        float acc[8] = {};
        #pragma unroll
        for (int ld = 0; ld < 8; ++ld) {
            int idx = (p << 4) + (ld << 1) + half;
            unsigned int off = soffB[idx];
            float wgt = swB[idx];
            short8 v = *(const short8*)(fbase + off);
            union { short8 s; unsigned int u[4]; } uv;
            uv.s = v;
            #pragma unroll
            for (int k2 = 0; k2 < 4; ++k2) {
                unsigned int u = uv.u[k2];
                float flo = __uint_as_float(u << 16);
                float fhi = __uint_as_float(u & 0xffff0000u);
                acc[k2 * 2]     += wgt * flo;
                acc[k2 * 2 + 1] += wgt * fhi;
            }
        }
        short8 o;
        #pragma unroll
        for (int j = 0; j < 8; ++j) {
            float t = acc[j] + __shfl_xor(acc[j], 32);
            o[j] = f2bf(t);
        }
        if (half == 0) *(short8*)&outb[p * 264 + (ch16 << 3)] = o;
    }
    __syncthreads();
    int c = tid / 49, r = tid % 49;
    short* xrow = Xb + (long)roi * 12544;
    #pragma unroll 1
    for (int i = 0; i < 49; ++i) {
        xrow[tid + i * 256] = outb[r * 264 + c];
        c += 5; r += 11;
        if (r >= 49) { r -= 49; c += 1; }
    }
}

// ---- FC1: 128x128 tile, BK=32, dbuf 2-phase, 32KB LDS -> 4-5 blocks/CU ----
// P[z][M][N] = A[M,Kslice] @ Bt[N,Kslice]^T (bf16 partials, no bias)
// rows are 64B (4 x 16B chunks); read chunk = lk ^ ((lr^(lr>>2))&3) (uniform 2-way,
// free); glds source pre-permuted with the same involution, LDS dest linear.
__global__ __launch_bounds__(256) void gemm128k32(const short* __restrict__ A,
                                                  const short* __restrict__ Bt,
                                                  short* __restrict__ Cout,
                                                  int M, int N, int K, int kbase, int krem) {
    __shared__ short As[2][128 * 32];   // 2 x 8KB
    __shared__ short Bs[2][128 * 32];   // 2 x 8KB -> 32KB total
    int gx = gridDim.x, gy = gridDim.y;
    int nwg = gx * gy * gridDim.z;
    int orig = blockIdx.x + gx * (blockIdx.y + gy * blockIdx.z);
    int wg = orig;
    if ((nwg & 7) == 0 && nwg >= 64) {
        int q = nwg >> 3;
        wg = (orig & 7) * q + (orig >> 3);
    }
    int bx_ = wg % gx;
    int tmp = wg / gx;
    int by_ = tmp % gy;
    int bz_ = tmp / gy;
    int ksteps = kbase + (bz_ < krem ? 1 : 0);
    long kbeg = ((long)bz_ * kbase + (bz_ < krem ? bz_ : krem)) * 32;   // elements
    int m0 = by_ * 128, n0 = bx_ * 128;
    int tid = threadIdx.x;
    int w = tid >> 6, lane = tid & 63;
    int wr = w >> 1, wc = w & 1;
    int lr = lane & 15, lk = lane >> 4;           // lk 0..3
    // staging: srow = tid>>2 (0..63, +64 on 2nd pass), source chunk pre-swizzled
    int srow = tid >> 2;
    int fsrow = (srow ^ (srow >> 2)) & 3;
    int sbx = ((tid & 3) ^ fsrow) << 4;
    const char* Ag = (const char*)A + ((long)(m0 + srow) * K + kbeg) * 2 + sbx;
    const char* Bg = (const char*)Bt + ((long)(n0 + srow) * K + kbeg) * 2 + sbx;
    const long rstep = (long)K * 128;             // 64 rows * K * 2B
    char* As0 = (char*)&As[0][0];
    char* Bs0 = (char*)&Bs[0][0];
    int wofs = w << 10;                           // wave writes 1KB per pass
    int flr = (lr ^ (lr >> 2)) & 3;
    int sw = ((lk ^ flr) & 3) << 4;               // read chunk swizzle
    f32x4 acc[4][4] = {};

    // stage tile t (64B per row) into buffer b: 2 passes per operand
    #define STG(t, b) do { \
        const char* _a = Ag + (long)(t) * 64; \
        const char* _b = Bg + (long)(t) * 64; \
        char* _ad = As0 + ((b) << 13) + wofs; \
        char* _bd = Bs0 + ((b) << 13) + wofs; \
        GLDS16(_a, _ad);         GLDS16(_a + rstep, _ad + 4096); \
        GLDS16(_b, _bd);         GLDS16(_b + rstep, _bd + 4096); \
    } while (0)

    STG(0, 0);
    __syncthreads();
    int cur = 0;
    for (int t = 0; t < ksteps; ++t) {
        if (t + 1 < ksteps) STG(t + 1, cur ^ 1);  // issue next stage BEFORE compute
        const char* as = As0 + (cur << 13);
        const char* bs = Bs0 + (cur << 13);
        short8 av[4], bv[4];
        #pragma unroll
        for (int f = 0; f < 4; ++f) {
            av[f] = *(const short8*)(as + (wr * 64 + f * 16 + lr) * 64 + sw);
            bv[f] = *(const short8*)(bs + (wc * 64 + f * 16 + lr) * 64 + sw);
        }
        #pragma unroll
        for (int fm = 0; fm < 4; ++fm)
            #pragma unroll
            for (int fn = 0; fn < 4; ++fn)
                acc[fm][fn] = __builtin_amdgcn_mfma_f32_16x16x32_bf16(av[fm], bv[fn], acc[fm][fn], 0, 0, 0);
        __syncthreads();
        cur ^= 1;
    }
    #undef STG

    #pragma unroll
    for (int fm = 0; fm < 4; ++fm) {
        #pragma unroll
        for (int fn = 0; fn < 4; ++fn) {
            int col = n0 + wc * 64 + fn * 16 + lr;
            #pragma unroll
            for (int j = 0; j < 4; ++j) {
                int row = m0 + wr * 64 + fm * 16 + lk * 4 + j;
                Cout[(long)bz_ * M * N + (long)row * N + col] = f2bf(acc[fm][fn][j]);
            }
        }
    }
}

// ---------------- 128x128 MFMA GEMM BK=64 (FC2/head), glds + swizzle + dbuf ----------
// MODE 1: bias+relu -> bf16; MODE 2: (bc|bb|0) bias -> f32, store col < Ncap
template <int MODE>
__global__ __launch_bounds__(256) void gemm128(const short* __restrict__ A,
                                               const short* __restrict__ Bt,
                                               const float* __restrict__ bias,
                                               const float* __restrict__ bias2,
                                               void* __restrict__ Cout,
                                               int M, int N, int K, int kbase, int krem,
                                               int Ncap) {
    __shared__ short As[2][128 * 64];
    __shared__ short Bs[2][128 * 64];
    int gx = gridDim.x, gy = gridDim.y;
    int nwg = gx * gy * gridDim.z;
    int orig = blockIdx.x + gx * (blockIdx.y + gy * blockIdx.z);
    int wg = orig;
    if ((nwg & 7) == 0 && nwg >= 64) {
        int q = nwg >> 3;
        wg = (orig & 7) * q + (orig >> 3);
    }
    int bx_ = wg % gx;
    int tmp = wg / gx;
    int by_ = tmp % gy;
    int bz_ = tmp / gy;
    int ksteps = kbase + (bz_ < krem ? 1 : 0);
    long kbeg = ((long)bz_ * kbase + (bz_ < krem ? bz_ : krem)) * 64;
    int m0 = by_ * 128, n0 = bx_ * 128;
    int tid = threadIdx.x;
    int w = tid >> 6, lane = tid & 63;
    int wr = w >> 1, wc = w & 1;
    int lr = lane & 15, lk = lane >> 4;
    int srow = tid >> 3;
    int sbx = ((tid & 7) ^ (srow & 7)) << 4;
    const char* Ag = (const char*)A + ((long)(m0 + srow) * K + kbeg) * 2 + sbx;
    const char* Bg = (const char*)Bt + ((long)(n0 + srow) * K + kbeg) * 2 + sbx;
    const long rstep = (long)K * 64;
    char* As0 = (char*)&As[0][0];
    char* Bs0 = (char*)&Bs[0][0];
    int wofs = w << 10;
    int sw = (lr & 7) << 4;
    f32x4 acc[4][4] = {};

    #pragma unroll
    for (int i = 0; i < 4; ++i) {
        GLDS16(Ag + i * rstep, As0 + wofs + i * 4096);
        GLDS16(Bg + i * rstep, Bs0 + wofs + i * 4096);
    }
    __syncthreads();
    int cur = 0;
    for (int t = 0; t < ksteps; ++t) {
        if (t + 1 < ksteps) {
            const char* a = Ag + (long)(t + 1) * 128;
            const char* b = Bg + (long)(t + 1) * 128;
            char* ad = As0 + ((cur ^ 1) << 14) + wofs;
            char* bd = Bs0 + ((cur ^ 1) << 14) + wofs;
            #pragma unroll
            for (int i = 0; i < 4; ++i) {
                GLDS16(a + i * rstep, ad + i * 4096);
                GLDS16(b + i * rstep, bd + i * 4096);
            }
        }
        const char* as = As0 + (cur << 14);
        const char* bs = Bs0 + (cur << 14);
        #pragma unroll
        for (int kk = 0; kk < 2; ++kk) {
            short8 av[4], bv[4];
            #pragma unroll
            for (int f = 0; f < 4; ++f) {
                av[f] = *(const short8*)(as + (wr * 64 + f * 16 + lr) * 128 + ((kk * 64 + lk * 16) ^ sw));
                bv[f] = *(const short8*)(bs + (wc * 64 + f * 16 + lr) * 128 + ((kk * 64 + lk * 16) ^ sw));
            }
            #pragma unroll
            for (int fm = 0; fm < 4; ++fm)
                #pragma unroll
                for (int fn = 0; fn < 4; ++fn)
                    acc[fm][fn] = __builtin_amdgcn_mfma_f32_16x16x32_bf16(av[fm], bv[fn], acc[fm][fn], 0, 0, 0);
        }
        __syncthreads();
        cur ^= 1;
    }
    #pragma unroll
    for (int fm = 0; fm < 4; ++fm) {
        #pragma unroll
        for (int fn = 0; fn < 4; ++fn) {
            int col = n0 + wc * 64 + fn * 16 + lr;
            float bv = 0.f;
            if (MODE == 1) bv = bias[col];
            if (MODE == 2) bv = (col < 81) ? bias[col] : (col < 405 ? bias2[col - 81] : 0.f);
            #pragma unroll
            for (int j = 0; j < 4; ++j) {
                int row = m0 + wr * 64 + fm * 16 + lk * 4 + j;
                float v = acc[fm][fn][j];
                if (MODE == 1) {
                    ((short*)Cout)[(long)row * N + col] = f2bf(fmaxf(v + bv, 0.f));
                } else {
                    if (col < Ncap) ((float*)Cout)[(long)row * N + col] = v + bv;
                }
            }
        }
    }
}

// ---------------- split-K reduce: H1 = relu(sum_s P[s] + b1) -> bf16 ----------------
__global__ void reduceN_relu(const short* __restrict__ P, const float* __restrict__ bias,
                             short* __restrict__ Hout, int nsl) {
    long i0 = ((long)blockIdx.x * 256 + threadIdx.x) * 8;
    int col = (int)(i0 & 1023);
    float v[8];
    #pragma unroll
    for (int j = 0; j < 8; ++j) v[j] = bias[col + j];
    for (int s = 0; s < nsl; ++s) {
        short8 p = *(const short8*)(P + (long)s * 1048576 + i0);
        #pragma unroll
        for (int j = 0; j < 8; ++j) v[j] += bf2f(p[j]);
    }
    short8 o;
    #pragma unroll
    for (int j = 0; j < 8; ++j) o[j] = f2bf(fmaxf(v[j], 0.f));
    *(short8*)(Hout + i0) = o;
}

// ---------------- softmax + decode + valid ----------------
__global__ void head_epilogue(const float* __restrict__ O,      // [1024][448]
                              const float* __restrict__ props,
                              float* __restrict__ Boxes,
                              float* __restrict__ Scores,
                              unsigned char* __restrict__ Valid) {
    int roi = blockIdx.x;
    int lane = threadIdx.x;  // 64
    const float* o = O + (long)roi * 448;
    float m = -1e30f;
    for (int i = lane; i < 81; i += 64) m = fmaxf(m, o[i]);
    for (int off = 32; off > 0; off >>= 1) m = fmaxf(m, __shfl_xor(m, off));
    float ssum = 0.f;
    for (int i = lane; i < 81; i += 64) ssum += expf(o[i] - m);
    for (int off = 32; off > 0; off >>= 1) ssum += __shfl_xor(ssum, off);
    float inv = 1.0f / ssum;
    int img = roi >> 9, rb = roi & 511;
    float px1 = props[roi * 4 + 0], py1 = props[roi * 4 + 1];
    float px2 = props[roi * 4 + 2], py2 = props[roi * 4 + 3];
    float w = px2 - px1, h = py2 - py1;
    float cx = px1 + 0.5f * w, cy = py1 + 0.5f * h;
    long obase = (long)img * 40960 + (long)rb * 80;
    const float DW = 4.135166556742356f;
    for (int t = lane; t < 80; t += 64) {
        int cls = t + 1;
        float score = expf(o[cls] - m) * inv;
        const float* d = o + 81 + cls * 4;
        float dx = d[0] * 0.1f, dy = d[1] * 0.1f;
        float dw = fminf(d[2] * 0.2f, DW);
        float dh = fminf(d[3] * 0.2f, DW);
        float pcx = dx * w + cx, pcy = dy * h + cy;
        float pw = expf(dw) * w, ph = expf(dh) * h;
        float x1 = pcx - 0.5f * pw, y1 = pcy - 0.5f * ph;
        float x2 = pcx + 0.5f * pw, y2 = pcy + 0.5f * ph;
        x1 = fminf(fmaxf(x1, 0.f), 800.f); y1 = fminf(fmaxf(y1, 0.f), 800.f);
        x2 = fminf(fmaxf(x2, 0.f), 800.f); y2 = fminf(fmaxf(y2, 0.f), 800.f);
        float wv = x2 - x1, hv = y2 - y1;
        long oi = obase + t;
        Boxes[oi * 4 + 0] = x1; Boxes[oi * 4 + 1] = y1;
        Boxes[oi * 4 + 2] = x2; Boxes[oi * 4 + 3] = y2;
        Scores[oi] = score;
        Valid[oi] = (score >= 0.05f && wv >= 1.0f && hv >= 1.0f) ? 1 : 0;
    }
}

// ---------------- fused compaction + greedy NMS (one block per image) ----------------
__global__ void nms_fused(const float* __restrict__ Boxes, const float* __restrict__ Scores,
                          const unsigned char* __restrict__ Valid,
                          float* __restrict__ CB, int* __restrict__ CL,
                          float* __restrict__ CSw, float* __restrict__ out) {
    int img = blockIdx.x;
    int tid = threadIdx.x;  // 256
    const int SEG = 160;
    const unsigned char* V = Valid + (long)img * 40960;
    int j0 = tid * SEG;
    const unsigned int* V4 = (const unsigned int*)(V + j0);
    int c = 0;
    #pragma unroll
    for (int k = 0; k < 40; ++k) {
        unsigned int u = V4[k];
        c += (int)((u * 0x01010101u) >> 24);
    }
    __shared__ int cnt[256];
    cnt[tid] = c;
    __syncthreads();
    for (int d = 1; d < 256; d <<= 1) {
        int v = (tid >= d) ? cnt[tid - d] : 0;
        __syncthreads();
        cnt[tid] += v;
        __syncthreads();
    }
    int pos = cnt[tid] - c;
    const float* B = Boxes + (long)img * 40960 * 4;
    const float* S = Scores + (long)img * 40960;
    float* cb = CB + (long)img * 40960 * 4;
    float* sc = CSw + (long)img * 40960;
    int* cl = CL + (long)img * 40960;
    if (c > 0) {
        for (int k = 0; k < SEG; ++k) {
            int j = j0 + k;
            if (V[j]) {
                sc[pos] = S[j];
                cb[pos * 4 + 0] = B[j * 4 + 0]; cb[pos * 4 + 1] = B[j * 4 + 1];
                cb[pos * 4 + 2] = B[j * 4 + 2]; cb[pos * 4 + 3] = B[j * 4 + 3];
                cl[pos] = (j % 80) + 1;
                ++pos;
            }
        }
    }
    int Vn = cnt[255];
    for (int i = tid; i < 400; i += 256) out[img * 400 + i] = 0.f;
    if (tid < 100) {
        out[800 + img * 100 + tid] = 0.f;
        out[1000 + img * 100 + tid] = 0.f;
        out[1200 + img * 100 + tid] = 0.f;
    }
    __syncthreads();
    __shared__ float rv[256];
    __shared__ int ri[256];
    __shared__ float selbox[4];
    const float NEG = -__builtin_inff();
    for (int det = 0; det < 100; ++det) {
        float bv = NEG; int bi = -1;
        for (int j = tid; j < Vn; j += 256) {
            float s = sc[j];
            if (s > bv) { bv = s; bi = j; }
        }
        rv[tid] = bv; ri[tid] = bi;
        __syncthreads();
        for (int off = 128; off > 0; off >>= 1) {
            if (tid < off) {
                float ov = rv[tid + off]; int oi = ri[tid + off];
                if (ov > rv[tid] ||
                    (ov == rv[tid] && oi != -1 && (ri[tid] == -1 || oi < ri[tid]))) {
                    rv[tid] = ov; ri[tid] = oi;
                }
            }
            __syncthreads();
        }
        float mval = rv[0]; int mi = ri[0];
        if (!(mval > NEG) || mi < 0) break;
        if (tid == 0) {
            out[img * 400 + det * 4 + 0] = cb[mi * 4 + 0];
            out[img * 400 + det * 4 + 1] = cb[mi * 4 + 1];
            out[img * 400 + det * 4 + 2] = cb[mi * 4 + 2];
            out[img * 400 + det * 4 + 3] = cb[mi * 4 + 3];
            out[800 + img * 100 + det] = mval;
            out[1000 + img * 100 + det] = (float)cl[mi];
            out[1200 + img * 100 + det] = 1.0f;
            selbox[0] = cb[mi * 4 + 0]; selbox[1] = cb[mi * 4 + 1];
            selbox[2] = cb[mi * 4 + 2]; selbox[3] = cb[mi * 4 + 3];
            sc[mi] = NEG;
        }
        __syncthreads();
        float bx1 = selbox[0], by1 = selbox[1], bx2 = selbox[2], by2 = selbox[3];
        float a1 = (bx2 - bx1) * (by2 - by1);
        for (int j = tid; j < Vn; j += 256) {
            float s = sc[j];
            if (s == NEG) continue;
            float x1 = fmaxf(bx1, cb[j * 4 + 0]), y1 = fmaxf(by1, cb[j * 4 + 1]);
            float x2 = fminf(bx2, cb[j * 4 + 2]), y2 = fminf(by2, cb[j * 4 + 3]);
            float iw = fmaxf(x2 - x1, 0.f), ih = fmaxf(y2 - y1, 0.f);
            float inter = iw * ih;
            float a2 = (cb[j * 4 + 2] - cb[j * 4 + 0]) * (cb[j * 4 + 3] - cb[j * 4 + 1]);
            float iou = inter / (a1 + a2 - inter + 1e-9f);
            if (iou > 0.5f) sc[j] = NEG;
        }
        __syncthreads();
    }
}

extern "C" void kernel_launch(void* const* d_in, const int* in_sizes, int n_in,
                              void* d_out, int out_size, void* d_ws, size_t ws_size,
                              hipStream_t stream) {
    const float* features  = (const float*)d_in[0];
    const float* proposals = (const float*)d_in[1];
    const float* W1 = (const float*)d_in[2];
    const float* b1 = (const float*)d_in[3];
    const float* W2 = (const float*)d_in[4];
    const float* b2 = (const float*)d_in[5];
    const float* Wc = (const float*)d_in[6];
    const float* bc = (const float*)d_in[7];
    const float* Wb = (const float*)d_in[8];
    const float* bb = (const float*)d_in[9];

    // FC1 split-K tier: K-steps at BK=32 = 392. z=16 -> 1024 blocks (4/CU resident).
    int zf1, kb1, kr1;
    if (ws_size >= 51380224UL + 16UL * 2097152UL + 3145728UL) { zf1 = 16; kb1 = 24; kr1 = 8; }
    else if (ws_size >= 51380224UL + 8UL * 2097152UL + 3145728UL) { zf1 = 8; kb1 = 49; kr1 = 0; }
    else { zf1 = 4; kb1 = 98; kr1 = 0; }

    char* ws = (char*)d_ws;
    // phase A
    short* Xb    = (short*)(ws);                      // 25,690,112 B
    short* W1t   = (short*)(ws + 25690112);           // 25,690,112 B
    short* featT = (short*)(ws + 51380224);           // 2,560,000 B (dead before P written)
    short* P     = (short*)(ws + 51380224);           // [zf1][1024][1024] bf16
    short* W2t_e = (short*)(ws + 51380224 + (size_t)zf1 * 2097152);  // 2MB
    short* Wht_e = (short*)((char*)W2t_e + 2097152);                 // 1MB
    // phase B (reuses ex-Xb region after FC1)
    short* H1b   = (short*)(ws);                      // 2 MB
    short* H2b   = (short*)(ws + 5242880);            // 2 MB
    float* Obuf  = (float*)(ws + 7340032);            // [1024][448] f32
    float* Boxes = (float*)(ws + 9175040);
    float* Scores= (float*)(ws + 10485760);
    unsigned char* Valid = (unsigned char*)(ws + 10813440);
    float* CB    = (float*)(ws + 10895360);
    int*   CL    = (int*)(ws + 12206080);
    float* CSw   = (float*)(ws + 12533760);

    transpose_v2<<<3840, 256, 0, stream>>>(W1, features, W2, Wc, Wb,
                                           W1t, featT, W2t_e, Wht_e);
    roi_align_v3<<<1024, 256, 0, stream>>>(featT, proposals, Xb);

    // FC1: BK=32 dbuf, z=16 split-K -> 4 blocks/CU
    gemm128k32<<<dim3(8, 8, zf1), 256, 0, stream>>>(Xb, W1t, P, 1024, 1024, 12544, kb1, kr1);
    reduceN_relu<<<512, 256, 0, stream>>>(P, b1, H1b, zf1);

    // FC2 + head: direct dbuf BK=64 (proven)
    gemm128<1><<<dim3(8, 8, 1), 256, 0, stream>>>(H1b, W2t_e, b2, nullptr, (void*)H2b,
                                                  1024, 1024, 1024, 16, 0, 1024);
    gemm128<2><<<dim3(4, 8, 1), 256, 0, stream>>>(H2b, Wht_e, bc, bb, (void*)Obuf,
                                                  1024, 448, 1024, 16, 0, 448);

    head_epilogue<<<1024, 64, 0, stream>>>(Obuf, proposals, Boxes, Scores, Valid);
    nms_fused<<<2, 256, 0, stream>>>(Boxes, Scores, Valid, CB, CL, CSw, (float*)d_out);
}

// Round 14
// 105.457 us; speedup vs baseline: 1.2525x; 1.2525x over previous
//
#include <hip/hip_runtime.h>
#include <hip/hip_bf16.h>

typedef __attribute__((ext_vector_type(8))) short short8;
typedef __attribute__((ext_vector_type(4))) float f32x4;
typedef __attribute__((ext_vector_type(8))) int i32x8;

__device__ inline short f2bf(float x) {
    union { __hip_bfloat16 b; short s; } u;
    u.b = __float2bfloat16(x);
    return u.s;
}
__device__ inline float bf2f(short s) {
    union { __hip_bfloat16 b; short s; } u;
    u.s = s;
    return __bfloat162float(u.b);
}

#define GLDS16(g, l) __builtin_amdgcn_global_load_lds( \
    (const __attribute__((address_space(1))) void*)(g), \
    (__attribute__((address_space(3))) void*)(l), 16, 0, 0)

// pack 4 floats -> 4 fp8 e4m3 bytes (OCP on gfx950)
__device__ inline int pk4fp8(float a, float b, float c, float d) {
    int v = __builtin_amdgcn_cvt_pk_fp8_f32(a, b, 0, 0);
    v = __builtin_amdgcn_cvt_pk_fp8_f32(c, d, v, 1);
    return v;
}

// ------- transpose v2: 64x64 tiles, float4 loads; W1 -> fp8(x64), rest -> bf16 -------
// jobs: [0,3136) W1 | [3136,3456) features x2 | [3456,3712) W2 | [3712,3744) Wc
//       | [3744,3840) Wb
__global__ __launch_bounds__(256) void transpose_v2(const float* __restrict__ W1,
                                                    const float* __restrict__ features,
                                                    const float* __restrict__ W2,
                                                    const float* __restrict__ Wc,
                                                    const float* __restrict__ Wb,
                                                    unsigned char* __restrict__ W1t8,
                                                    short* __restrict__ featT,
                                                    short* __restrict__ W2t,
                                                    short* __restrict__ Wht) {
    __shared__ float tile[64][65];
    int id = blockIdx.x;
    const float* in;
    short* out = nullptr;
    int R, C, r0, c0;
    int isfp8 = 0;
    if (id < 3136) {
        in = W1; isfp8 = 1; R = 12544; C = 1024;
        r0 = (id % 196) * 64; c0 = (id / 196) * 64;
    } else if (id < 3456) {
        int f = id - 3136;
        int img = f / 160, g = f % 160;
        in = features + (long)img * 640000;
        out = featT + (long)img * 640000;
        R = 256; C = 2500;
        r0 = (g % 4) * 64; c0 = (g / 4) * 64;
    } else if (id < 3712) {
        int g = id - 3456;
        in = W2; out = W2t; R = 1024; C = 1024;
        r0 = (g % 16) * 64; c0 = (g / 16) * 64;
    } else if (id < 3744) {
        int g = id - 3712;
        in = Wc; out = Wht; R = 1024; C = 81;
        r0 = (g % 16) * 64; c0 = (g / 16) * 64;
    } else {
        int g = id - 3744;
        in = Wb; out = Wht + 81 * 1024; R = 1024; C = 324;
        r0 = (g % 16) * 64; c0 = (g / 16) * 64;
    }
    int tid = threadIdx.x;
    int tr = tid >> 4, tc = tid & 15;
    if (c0 + 64 <= C) {
        #pragma unroll
        for (int i = 0; i < 4; ++i) {
            int r = r0 + tr + i * 16;
            float4 v = *(const float4*)(in + (long)r * C + c0 + tc * 4);
            tile[tr + i * 16][tc * 4 + 0] = v.x;
            tile[tr + i * 16][tc * 4 + 1] = v.y;
            tile[tr + i * 16][tc * 4 + 2] = v.z;
            tile[tr + i * 16][tc * 4 + 3] = v.w;
        }
    } else {
        #pragma unroll
        for (int i = 0; i < 4; ++i) {
            int r = r0 + tr + i * 16;
            #pragma unroll
            for (int e = 0; e < 4; ++e) {
                int c = c0 + tc * 4 + e;
                tile[tr + i * 16][tc * 4 + e] = (c < C) ? in[(long)r * C + c] : 0.f;
            }
        }
    }
    __syncthreads();
    #pragma unroll
    for (int p = 0; p < 2; ++p) {
        int n = (tid >> 3) + p * 32;
        int k0 = (tid & 7) * 8;
        if (c0 + n < C) {
            if (isfp8) {
                // W1 scaled by 64 into e4m3 normal range; compensated in reduce
                float v0 = tile[k0 + 0][n] * 64.f, v1 = tile[k0 + 1][n] * 64.f;
                float v2 = tile[k0 + 2][n] * 64.f, v3 = tile[k0 + 3][n] * 64.f;
                float v4 = tile[k0 + 4][n] * 64.f, v5 = tile[k0 + 5][n] * 64.f;
                float v6 = tile[k0 + 6][n] * 64.f, v7 = tile[k0 + 7][n] * 64.f;
                int2 w;
                w.x = pk4fp8(v0, v1, v2, v3);
                w.y = pk4fp8(v4, v5, v6, v7);
                *(int2*)(W1t8 + (long)(c0 + n) * R + r0 + k0) = w;
            } else {
                short8 o;
                #pragma unroll
                for (int j = 0; j < 8; ++j) o[j] = f2bf(tile[k0 + j][n]);
                *(short8*)(out + (long)(c0 + n) * R + r0 + k0) = o;
            }
        }
    }
}

// ---------------- ROI-align v3 -> X fp8 [1024][12544] ----------
__global__ __launch_bounds__(256) void roi_align_v3(const short* __restrict__ featT,
                                                    const float* __restrict__ props,
                                                    unsigned char* __restrict__ Xb) {
    int roi = blockIdx.x;
    int img = roi >> 9;
    __shared__ unsigned int soffB[784];
    __shared__ float swB[784];
    __shared__ float pbox[4];
    __shared__ unsigned char outb[49 * 264];
    int tid = threadIdx.x;
    if (tid < 4) pbox[tid] = props[roi * 4 + tid];
    __syncthreads();
    if (tid < 196) {
        float x1 = pbox[0] * 0.0625f, y1 = pbox[1] * 0.0625f;
        float x2 = pbox[2] * 0.0625f, y2 = pbox[3] * 0.0625f;
        float rw = fmaxf(x2 - x1, 1.0f), rh = fmaxf(y2 - y1, 1.0f);
        int p = tid >> 2, q = tid & 3;
        int py = p / 7, px = p % 7;
        int sy = q >> 1, sx = q & 1;
        int gy = py * 2 + sy, gx = px * 2 + sx;
        float gyv = ((float)gy + 0.5f) * 0.5f;
        float gxv = ((float)gx + 0.5f) * 0.5f;
        float ys = y1 + gyv * (rh * (1.0f / 7.0f));
        float xs = x1 + gxv * (rw * (1.0f / 7.0f));
        ys = fminf(fmaxf(ys, 0.0f), 49.0f);
        xs = fminf(fmaxf(xs, 0.0f), 49.0f);
        float y0f = floorf(ys), x0f = floorf(xs);
        int y0 = (int)y0f, x0 = (int)x0f;
        int y1i = min(y0 + 1, 49), x1i = min(x0 + 1, 49);
        float ly = ys - y0f, lx = xs - x0f;
        float hy = 1.f - ly, hx = 1.f - lx;
        int b00 = (y0 * 50 + x0) << 9;
        int ddx = (x1i - x0) << 9;
        int ddy = (y1i - y0) * 25600;
        int t4 = tid << 2;
        soffB[t4 + 0] = b00;             swB[t4 + 0] = hy * hx * 0.25f;
        soffB[t4 + 1] = b00 + ddx;       swB[t4 + 1] = hy * lx * 0.25f;
        soffB[t4 + 2] = b00 + ddy;       swB[t4 + 2] = ly * hx * 0.25f;
        soffB[t4 + 3] = b00 + ddy + ddx; swB[t4 + 3] = ly * lx * 0.25f;
    }
    __syncthreads();
    int w = tid >> 6, l = tid & 63;
    int half = l >> 5, ch16 = l & 31;
    const char* fbase = (const char*)featT + (long)img * 1280000 + (ch16 << 4);
    for (int p = w; p < 49; p += 4) {
        float acc[8] = {};
        #pragma unroll
        for (int ld = 0; ld < 8; ++ld) {
            int idx = (p << 4) + (ld << 1) + half;
            unsigned int off = soffB[idx];
            float wgt = swB[idx];
            short8 v = *(const short8*)(fbase + off);
            union { short8 s; unsigned int u[4]; } uv;
            uv.s = v;
            #pragma unroll
            for (int k2 = 0; k2 < 4; ++k2) {
                unsigned int u = uv.u[k2];
                float flo = __uint_as_float(u << 16);
                float fhi = __uint_as_float(u & 0xffff0000u);
                acc[k2 * 2]     += wgt * flo;
                acc[k2 * 2 + 1] += wgt * fhi;
            }
        }
        float t[8];
        #pragma unroll
        for (int j = 0; j < 8; ++j) t[j] = acc[j] + __shfl_xor(acc[j], 32);
        if (half == 0) {
            int2 o;
            o.x = pk4fp8(t[0], t[1], t[2], t[3]);
            o.y = pk4fp8(t[4], t[5], t[6], t[7]);
            *(int2*)&outb[p * 264 + (ch16 << 3)] = o;
        }
    }
    __syncthreads();
    int c = tid / 49, r = tid % 49;
    unsigned char* xrow = Xb + (long)roi * 12544;
    #pragma unroll 1
    for (int i = 0; i < 49; ++i) {
        xrow[tid + i * 256] = outb[r * 264 + c];
        c += 5; r += 11;
        if (r >= 49) { r -= 49; c += 1; }
    }
}

// ---- FC1: fp8 MX MFMA 16x16x128 (scale=1.0), 128x128 tile, BK=128 elems = 128B rows,
//      dbuf 2-phase glds + chunk-XOR swizzle (addressing identical to proven bf16 kernel).
//      P[z][M][N] bf16 partials (values x64 from weight scaling).
__global__ __launch_bounds__(256) void gemm128f8(const unsigned char* __restrict__ A,
                                                 const unsigned char* __restrict__ Bt,
                                                 short* __restrict__ Cout,
                                                 int M, int N, int K, int kbase, int krem) {
    __shared__ char As[2][16384];
    __shared__ char Bs[2][16384];
    int gx = gridDim.x, gy = gridDim.y;
    int nwg = gx * gy * gridDim.z;
    int orig = blockIdx.x + gx * (blockIdx.y + gy * blockIdx.z);
    int wg = orig;
    if ((nwg & 7) == 0 && nwg >= 64) {
        int q = nwg >> 3;
        wg = (orig & 7) * q + (orig >> 3);
    }
    int bx_ = wg % gx;
    int tmp = wg / gx;
    int by_ = tmp % gy;
    int bz_ = tmp / gy;
    int ksteps = kbase + (bz_ < krem ? 1 : 0);
    long kbeg = ((long)bz_ * kbase + (bz_ < krem ? bz_ : krem)) * 128;   // bytes = elems
    int m0 = by_ * 128, n0 = bx_ * 128;
    int tid = threadIdx.x;
    int w = tid >> 6, lane = tid & 63;
    int wr = w >> 1, wc = w & 1;
    int lr = lane & 15, lk = lane >> 4;
    int srow = tid >> 3;
    int sbx = ((tid & 7) ^ (srow & 7)) << 4;
    const unsigned char* Ag = A + (long)(m0 + srow) * K + kbeg + sbx;
    const unsigned char* Bg = Bt + (long)(n0 + srow) * K + kbeg + sbx;
    const long rstep = (long)K * 32;   // 32 rows per staging pass
    char* As0 = (char*)&As[0][0];
    char* Bs0 = (char*)&Bs[0][0];
    int wofs = w << 10;
    f32x4 acc[4][4] = {};

    #pragma unroll
    for (int i = 0; i < 4; ++i) {
        GLDS16(Ag + i * rstep, As0 + wofs + i * 4096);
        GLDS16(Bg + i * rstep, Bs0 + wofs + i * 4096);
    }
    __syncthreads();
    int cur = 0;
    const int sc1 = 0x7f7f7f7f;   // e8m0 = 127 -> scale 1.0 for all blocks
    for (int t = 0; t < ksteps; ++t) {
        if (t + 1 < ksteps) {   // issue next-tile stage BEFORE compute
            const unsigned char* a = Ag + (long)(t + 1) * 128;
            const unsigned char* b = Bg + (long)(t + 1) * 128;
            char* ad = As0 + ((cur ^ 1) << 14) + wofs;
            char* bd = Bs0 + ((cur ^ 1) << 14) + wofs;
            #pragma unroll
            for (int i = 0; i < 4; ++i) {
                GLDS16(a + i * rstep, ad + i * 4096);
                GLDS16(b + i * rstep, bd + i * 4096);
            }
        }
        const char* as = As0 + (cur << 14);
        const char* bs = Bs0 + (cur << 14);
        i32x8 av[4], bv[4];
        #pragma unroll
        for (int f = 0; f < 4; ++f) {
            int ra = wr * 64 + f * 16 + lr;
            int rb = wc * 64 + f * 16 + lr;
            int c0 = lk * 2;
            union { i32x8 v; f32x4 h[2]; } ua, ub;
            ua.h[0] = *(const f32x4*)(as + ra * 128 + (((c0 + 0) ^ (ra & 7)) << 4));
            ua.h[1] = *(const f32x4*)(as + ra * 128 + (((c0 + 1) ^ (ra & 7)) << 4));
            ub.h[0] = *(const f32x4*)(bs + rb * 128 + (((c0 + 0) ^ (rb & 7)) << 4));
            ub.h[1] = *(const f32x4*)(bs + rb * 128 + (((c0 + 1) ^ (rb & 7)) << 4));
            av[f] = ua.v; bv[f] = ub.v;
        }
        #pragma unroll
        for (int fm = 0; fm < 4; ++fm)
            #pragma unroll
            for (int fn = 0; fn < 4; ++fn)
                acc[fm][fn] = __builtin_amdgcn_mfma_scale_f32_16x16x128_f8f6f4(
                    av[fm], bv[fn], acc[fm][fn], 0, 0, 0, sc1, 0, sc1);
        __syncthreads();
        cur ^= 1;
    }
    #pragma unroll
    for (int fm = 0; fm < 4; ++fm) {
        #pragma unroll
        for (int fn = 0; fn < 4; ++fn) {
            int col = n0 + wc * 64 + fn * 16 + lr;
            #pragma unroll
            for (int j = 0; j < 4; ++j) {
                int row = m0 + wr * 64 + fm * 16 + lk * 4 + j;
                Cout[(long)bz_ * M * N + (long)row * N + col] = f2bf(acc[fm][fn][j]);
            }
        }
    }
}

// ---------------- 128x128 bf16 MFMA GEMM BK=64 (FC2/head), glds + swizzle + dbuf ------
// MODE 1: bias+relu -> bf16; MODE 2: (bc|bb|0) bias -> f32, store col < Ncap
template <int MODE>
__global__ __launch_bounds__(256) void gemm128(const short* __restrict__ A,
                                               const short* __restrict__ Bt,
                                               const float* __restrict__ bias,
                                               const float* __restrict__ bias2,
                                               void* __restrict__ Cout,
                                               int M, int N, int K, int kbase, int krem,
                                               int Ncap) {
    __shared__ short As[2][128 * 64];
    __shared__ short Bs[2][128 * 64];
    int gx = gridDim.x, gy = gridDim.y;
    int nwg = gx * gy * gridDim.z;
    int orig = blockIdx.x + gx * (blockIdx.y + gy * blockIdx.z);
    int wg = orig;
    if ((nwg & 7) == 0 && nwg >= 64) {
        int q = nwg >> 3;
        wg = (orig & 7) * q + (orig >> 3);
    }
    int bx_ = wg % gx;
    int tmp = wg / gx;
    int by_ = tmp % gy;
    int bz_ = tmp / gy;
    int ksteps = kbase + (bz_ < krem ? 1 : 0);
    long kbeg = ((long)bz_ * kbase + (bz_ < krem ? bz_ : krem)) * 64;
    int m0 = by_ * 128, n0 = bx_ * 128;
    int tid = threadIdx.x;
    int w = tid >> 6, lane = tid & 63;
    int wr = w >> 1, wc = w & 1;
    int lr = lane & 15, lk = lane >> 4;
    int srow = tid >> 3;
    int sbx = ((tid & 7) ^ (srow & 7)) << 4;
    const char* Ag = (const char*)A + ((long)(m0 + srow) * K + kbeg) * 2 + sbx;
    const char* Bg = (const char*)Bt + ((long)(n0 + srow) * K + kbeg) * 2 + sbx;
    const long rstep = (long)K * 64;
    char* As0 = (char*)&As[0][0];
    char* Bs0 = (char*)&Bs[0][0];
    int wofs = w << 10;
    int sw = (lr & 7) << 4;
    f32x4 acc[4][4] = {};

    #pragma unroll
    for (int i = 0; i < 4; ++i) {
        GLDS16(Ag + i * rstep, As0 + wofs + i * 4096);
        GLDS16(Bg + i * rstep, Bs0 + wofs + i * 4096);
    }
    __syncthreads();
    int cur = 0;
    for (int t = 0; t < ksteps; ++t) {
        if (t + 1 < ksteps) {
            const char* a = Ag + (long)(t + 1) * 128;
            const char* b = Bg + (long)(t + 1) * 128;
            char* ad = As0 + ((cur ^ 1) << 14) + wofs;
            char* bd = Bs0 + ((cur ^ 1) << 14) + wofs;
            #pragma unroll
            for (int i = 0; i < 4; ++i) {
                GLDS16(a + i * rstep, ad + i * 4096);
                GLDS16(b + i * rstep, bd + i * 4096);
            }
        }
        const char* as = As0 + (cur << 14);
        const char* bs = Bs0 + (cur << 14);
        #pragma unroll
        for (int kk = 0; kk < 2; ++kk) {
            short8 av[4], bv[4];
            #pragma unroll
            for (int f = 0; f < 4; ++f) {
                av[f] = *(const short8*)(as + (wr * 64 + f * 16 + lr) * 128 + ((kk * 64 + lk * 16) ^ sw));
                bv[f] = *(const short8*)(bs + (wc * 64 + f * 16 + lr) * 128 + ((kk * 64 + lk * 16) ^ sw));
            }
            #pragma unroll
            for (int fm = 0; fm < 4; ++fm)
                #pragma unroll
                for (int fn = 0; fn < 4; ++fn)
                    acc[fm][fn] = __builtin_amdgcn_mfma_f32_16x16x32_bf16(av[fm], bv[fn], acc[fm][fn], 0, 0, 0);
        }
        __syncthreads();
        cur ^= 1;
    }
    #pragma unroll
    for (int fm = 0; fm < 4; ++fm) {
        #pragma unroll
        for (int fn = 0; fn < 4; ++fn) {
            int col = n0 + wc * 64 + fn * 16 + lr;
            float bv = 0.f;
            if (MODE == 1) bv = bias[col];
            if (MODE == 2) bv = (col < 81) ? bias[col] : (col < 405 ? bias2[col - 81] : 0.f);
            #pragma unroll
            for (int j = 0; j < 4; ++j) {
                int row = m0 + wr * 64 + fm * 16 + lk * 4 + j;
                float v = acc[fm][fn][j];
                if (MODE == 1) {
                    ((short*)Cout)[(long)row * N + col] = f2bf(fmaxf(v + bv, 0.f));
                } else {
                    if (col < Ncap) ((float*)Cout)[(long)row * N + col] = v + bv;
                }
            }
        }
    }
}

// --------- split-K reduce: H1 = relu(scale * sum_s P[s] + b1) -> bf16 ---------
__global__ void reduceN_relu(const short* __restrict__ P, const float* __restrict__ bias,
                             short* __restrict__ Hout, int nsl, float scale) {
    long i0 = ((long)blockIdx.x * 256 + threadIdx.x) * 8;
    int col = (int)(i0 & 1023);
    float v[8] = {};
    for (int s = 0; s < nsl; ++s) {
        short8 p = *(const short8*)(P + (long)s * 1048576 + i0);
        #pragma unroll
        for (int j = 0; j < 8; ++j) v[j] += bf2f(p[j]);
    }
    short8 o;
    #pragma unroll
    for (int j = 0; j < 8; ++j)
        o[j] = f2bf(fmaxf(fmaf(v[j], scale, bias[col + j]), 0.f));
    *(short8*)(Hout + i0) = o;
}

// ---------------- softmax + decode + valid ----------------
__global__ void head_epilogue(const float* __restrict__ O,      // [1024][448]
                              const float* __restrict__ props,
                              float* __restrict__ Boxes,
                              float* __restrict__ Scores,
                              unsigned char* __restrict__ Valid) {
    int roi = blockIdx.x;
    int lane = threadIdx.x;  // 64
    const float* o = O + (long)roi * 448;
    float m = -1e30f;
    for (int i = lane; i < 81; i += 64) m = fmaxf(m, o[i]);
    for (int off = 32; off > 0; off >>= 1) m = fmaxf(m, __shfl_xor(m, off));
    float ssum = 0.f;
    for (int i = lane; i < 81; i += 64) ssum += expf(o[i] - m);
    for (int off = 32; off > 0; off >>= 1) ssum += __shfl_xor(ssum, off);
    float inv = 1.0f / ssum;
    int img = roi >> 9, rb = roi & 511;
    float px1 = props[roi * 4 + 0], py1 = props[roi * 4 + 1];
    float px2 = props[roi * 4 + 2], py2 = props[roi * 4 + 3];
    float w = px2 - px1, h = py2 - py1;
    float cx = px1 + 0.5f * w, cy = py1 + 0.5f * h;
    long obase = (long)img * 40960 + (long)rb * 80;
    const float DW = 4.135166556742356f;
    for (int t = lane; t < 80; t += 64) {
        int cls = t + 1;
        float score = expf(o[cls] - m) * inv;
        const float* d = o + 81 + cls * 4;
        float dx = d[0] * 0.1f, dy = d[1] * 0.1f;
        float dw = fminf(d[2] * 0.2f, DW);
        float dh = fminf(d[3] * 0.2f, DW);
        float pcx = dx * w + cx, pcy = dy * h + cy;
        float pw = expf(dw) * w, ph = expf(dh) * h;
        float x1 = pcx - 0.5f * pw, y1 = pcy - 0.5f * ph;
        float x2 = pcx + 0.5f * pw, y2 = pcy + 0.5f * ph;
        x1 = fminf(fmaxf(x1, 0.f), 800.f); y1 = fminf(fmaxf(y1, 0.f), 800.f);
        x2 = fminf(fmaxf(x2, 0.f), 800.f); y2 = fminf(fmaxf(y2, 0.f), 800.f);
        float wv = x2 - x1, hv = y2 - y1;
        long oi = obase + t;
        Boxes[oi * 4 + 0] = x1; Boxes[oi * 4 + 1] = y1;
        Boxes[oi * 4 + 2] = x2; Boxes[oi * 4 + 3] = y2;
        Scores[oi] = score;
        Valid[oi] = (score >= 0.05f && wv >= 1.0f && hv >= 1.0f) ? 1 : 0;
    }
}

// ---------------- fused compaction + greedy NMS (one block per image) ----------------
__global__ void nms_fused(const float* __restrict__ Boxes, const float* __restrict__ Scores,
                          const unsigned char* __restrict__ Valid,
                          float* __restrict__ CB, int* __restrict__ CL,
                          float* __restrict__ CSw, float* __restrict__ out) {
    int img = blockIdx.x;
    int tid = threadIdx.x;  // 256
    const int SEG = 160;
    const unsigned char* V = Valid + (long)img * 40960;
    int j0 = tid * SEG;
    const unsigned int* V4 = (const unsigned int*)(V + j0);
    int c = 0;
    #pragma unroll
    for (int k = 0; k < 40; ++k) {
        unsigned int u = V4[k];
        c += (int)((u * 0x01010101u) >> 24);
    }
    __shared__ int cnt[256];
    cnt[tid] = c;
    __syncthreads();
    for (int d = 1; d < 256; d <<= 1) {
        int v = (tid >= d) ? cnt[tid - d] : 0;
        __syncthreads();
        cnt[tid] += v;
        __syncthreads();
    }
    int pos = cnt[tid] - c;
    const float* B = Boxes + (long)img * 40960 * 4;
    const float* S = Scores + (long)img * 40960;
    float* cb = CB + (long)img * 40960 * 4;
    float* sc = CSw + (long)img * 40960;
    int* cl = CL + (long)img * 40960;
    if (c > 0) {
        for (int k = 0; k < SEG; ++k) {
            int j = j0 + k;
            if (V[j]) {
                sc[pos] = S[j];
                cb[pos * 4 + 0] = B[j * 4 + 0]; cb[pos * 4 + 1] = B[j * 4 + 1];
                cb[pos * 4 + 2] = B[j * 4 + 2]; cb[pos * 4 + 3] = B[j * 4 + 3];
                cl[pos] = (j % 80) + 1;
                ++pos;
            }
        }
    }
    int Vn = cnt[255];
    for (int i = tid; i < 400; i += 256) out[img * 400 + i] = 0.f;
    if (tid < 100) {
        out[800 + img * 100 + tid] = 0.f;
        out[1000 + img * 100 + tid] = 0.f;
        out[1200 + img * 100 + tid] = 0.f;
    }
    __syncthreads();
    __shared__ float rv[256];
    __shared__ int ri[256];
    __shared__ float selbox[4];
    const float NEG = -__builtin_inff();
    for (int det = 0; det < 100; ++det) {
        float bv = NEG; int bi = -1;
        for (int j = tid; j < Vn; j += 256) {
            float s = sc[j];
            if (s > bv) { bv = s; bi = j; }
        }
        rv[tid] = bv; ri[tid] = bi;
        __syncthreads();
        for (int off = 128; off > 0; off >>= 1) {
            if (tid < off) {
                float ov = rv[tid + off]; int oi = ri[tid + off];
                if (ov > rv[tid] ||
                    (ov == rv[tid] && oi != -1 && (ri[tid] == -1 || oi < ri[tid]))) {
                    rv[tid] = ov; ri[tid] = oi;
                }
            }
            __syncthreads();
        }
        float mval = rv[0]; int mi = ri[0];
        if (!(mval > NEG) || mi < 0) break;
        if (tid == 0) {
            out[img * 400 + det * 4 + 0] = cb[mi * 4 + 0];
            out[img * 400 + det * 4 + 1] = cb[mi * 4 + 1];
            out[img * 400 + det * 4 + 2] = cb[mi * 4 + 2];
            out[img * 400 + det * 4 + 3] = cb[mi * 4 + 3];
            out[800 + img * 100 + det] = mval;
            out[1000 + img * 100 + det] = (float)cl[mi];
            out[1200 + img * 100 + det] = 1.0f;
            selbox[0] = cb[mi * 4 + 0]; selbox[1] = cb[mi * 4 + 1];
            selbox[2] = cb[mi * 4 + 2]; selbox[3] = cb[mi * 4 + 3];
            sc[mi] = NEG;
        }
        __syncthreads();
        float bx1 = selbox[0], by1 = selbox[1], bx2 = selbox[2], by2 = selbox[3];
        float a1 = (bx2 - bx1) * (by2 - by1);
        for (int j = tid; j < Vn; j += 256) {
            float s = sc[j];
            if (s == NEG) continue;
            float x1 = fmaxf(bx1, cb[j * 4 + 0]), y1 = fmaxf(by1, cb[j * 4 + 1]);
            float x2 = fminf(bx2, cb[j * 4 + 2]), y2 = fminf(by2, cb[j * 4 + 3]);
            float iw = fmaxf(x2 - x1, 0.f), ih = fmaxf(y2 - y1, 0.f);
            float inter = iw * ih;
            float a2 = (cb[j * 4 + 2] - cb[j * 4 + 0]) * (cb[j * 4 + 3] - cb[j * 4 + 1]);
            float iou = inter / (a1 + a2 - inter + 1e-9f);
            if (iou > 0.5f) sc[j] = NEG;
        }
        __syncthreads();
    }
}

extern "C" void kernel_launch(void* const* d_in, const int* in_sizes, int n_in,
                              void* d_out, int out_size, void* d_ws, size_t ws_size,
                              hipStream_t stream) {
    const float* features  = (const float*)d_in[0];
    const float* proposals = (const float*)d_in[1];
    const float* W1 = (const float*)d_in[2];
    const float* b1 = (const float*)d_in[3];
    const float* W2 = (const float*)d_in[4];
    const float* b2 = (const float*)d_in[5];
    const float* Wc = (const float*)d_in[6];
    const float* bc = (const float*)d_in[7];
    const float* Wb = (const float*)d_in[8];
    const float* bb = (const float*)d_in[9];

    // FC1 fp8 BK=128: 98 K-steps total. z=8 -> 512 blocks (2/CU).
    int zf1, kb1, kr1;
    if (ws_size >= 51380224UL + 8UL * 2097152UL + 3145728UL) { zf1 = 8; kb1 = 12; kr1 = 2; }
    else { zf1 = 4; kb1 = 24; kr1 = 2; }

    char* ws = (char*)d_ws;
    // phase A
    unsigned char* Xb  = (unsigned char*)(ws);        // [1024][12544] fp8, 12.8 MB
    unsigned char* W1t = (unsigned char*)(ws + 25690112);  // [1024][12544] fp8, 12.8 MB
    short* featT = (short*)(ws + 51380224);           // 2.56 MB (dead before P written)
    short* P     = (short*)(ws + 51380224);           // [zf1][1024][1024] bf16
    short* W2t_e = (short*)(ws + 51380224 + (size_t)zf1 * 2097152);  // 2 MB
    short* Wht_e = (short*)((char*)W2t_e + 2097152);                 // 1 MB
    // phase B (reuses ex-Xb region after FC1)
    short* H1b   = (short*)(ws);                      // 2 MB
    short* H2b   = (short*)(ws + 5242880);            // 2 MB
    float* Obuf  = (float*)(ws + 7340032);            // [1024][448] f32
    float* Boxes = (float*)(ws + 9175040);
    float* Scores= (float*)(ws + 10485760);
    unsigned char* Valid = (unsigned char*)(ws + 10813440);
    float* CB    = (float*)(ws + 10895360);
    int*   CL    = (int*)(ws + 12206080);
    float* CSw   = (float*)(ws + 12533760);

    transpose_v2<<<3840, 256, 0, stream>>>(W1, features, W2, Wc, Wb,
                                           W1t, featT, W2t_e, Wht_e);
    roi_align_v3<<<1024, 256, 0, stream>>>(featT, proposals, Xb);

    // FC1 in fp8 (MX scale=1), z split-K, partials x64 -> reduce with 1/64
    gemm128f8<<<dim3(8, 8, zf1), 256, 0, stream>>>(Xb, W1t, P, 1024, 1024, 12544, kb1, kr1);
    reduceN_relu<<<512, 256, 0, stream>>>(P, b1, H1b, zf1, 1.0f / 64.0f);

    // FC2 + head: bf16 direct dbuf BK=64 (proven)
    gemm128<1><<<dim3(8, 8, 1), 256, 0, stream>>>(H1b, W2t_e, b2, nullptr, (void*)H2b,
                                                  1024, 1024, 1024, 16, 0, 1024);
    gemm128<2><<<dim3(4, 8, 1), 256, 0, stream>>>(H2b, Wht_e, bc, bb, (void*)Obuf,
                                                  1024, 448, 1024, 16, 0, 448);

    head_epilogue<<<1024, 64, 0, stream>>>(Obuf, proposals, Boxes, Scores, Valid);
    nms_fused<<<2, 256, 0, stream>>>(Boxes, Scores, Valid, CB, CL, CSw, (float*)d_out);
}

// Round 15
// 95.279 us; speedup vs baseline: 1.3863x; 1.1068x over previous
//
#include <hip/hip_runtime.h>
#include <hip/hip_bf16.h>

typedef __attribute__((ext_vector_type(8))) short short8;
typedef __attribute__((ext_vector_type(4))) float f32x4;
typedef __attribute__((ext_vector_type(8))) int i32x8;

__device__ inline short f2bf(float x) {
    union { __hip_bfloat16 b; short s; } u;
    u.b = __float2bfloat16(x);
    return u.s;
}
__device__ inline float bf2f(short s) {
    union { __hip_bfloat16 b; short s; } u;
    u.s = s;
    return __bfloat162float(u.b);
}

#define GLDS16(g, l) __builtin_amdgcn_global_load_lds( \
    (const __attribute__((address_space(1))) void*)(g), \
    (__attribute__((address_space(3))) void*)(l), 16, 0, 0)

// pack 4 floats -> 4 fp8 e4m3 bytes (OCP on gfx950)
__device__ inline int pk4fp8(float a, float b, float c, float d) {
    int v = __builtin_amdgcn_cvt_pk_fp8_f32(a, b, 0, 0);
    v = __builtin_amdgcn_cvt_pk_fp8_f32(c, d, v, 1);
    return v;
}
__device__ inline unsigned char f2fp8(float a) {
    return (unsigned char)(__builtin_amdgcn_cvt_pk_fp8_f32(a, a, 0, 0) & 0xff);
}

// ------- transpose v2: 64x64 tiles; weights -> fp8(x64), features -> bf16 -------
// jobs: [0,3136) W1 | [3136,3456) features x2 | [3456,3712) W2 | [3712,3744) Wc
//       | [3744,3840) Wb
__global__ __launch_bounds__(256) void transpose_v2(const float* __restrict__ W1,
                                                    const float* __restrict__ features,
                                                    const float* __restrict__ W2,
                                                    const float* __restrict__ Wc,
                                                    const float* __restrict__ Wb,
                                                    unsigned char* __restrict__ W1t8,
                                                    short* __restrict__ featT,
                                                    unsigned char* __restrict__ W2t8,
                                                    unsigned char* __restrict__ Wht8) {
    __shared__ float tile[64][65];
    int id = blockIdx.x;
    const float* in;
    short* outb16 = nullptr;
    unsigned char* out8 = nullptr;
    int R, C, r0, c0;
    if (id < 3136) {
        in = W1; out8 = W1t8; R = 12544; C = 1024;
        r0 = (id % 196) * 64; c0 = (id / 196) * 64;
    } else if (id < 3456) {
        int f = id - 3136;
        int img = f / 160, g = f % 160;
        in = features + (long)img * 640000;
        outb16 = featT + (long)img * 640000;
        R = 256; C = 2500;
        r0 = (g % 4) * 64; c0 = (g / 4) * 64;
    } else if (id < 3712) {
        int g = id - 3456;
        in = W2; out8 = W2t8; R = 1024; C = 1024;
        r0 = (g % 16) * 64; c0 = (g / 16) * 64;
    } else if (id < 3744) {
        int g = id - 3712;
        in = Wc; out8 = Wht8; R = 1024; C = 81;
        r0 = (g % 16) * 64; c0 = (g / 16) * 64;
    } else {
        int g = id - 3744;
        in = Wb; out8 = Wht8 + 81 * 1024; R = 1024; C = 324;
        r0 = (g % 16) * 64; c0 = (g / 16) * 64;
    }
    int tid = threadIdx.x;
    int tr = tid >> 4, tc = tid & 15;
    if (c0 + 64 <= C) {
        #pragma unroll
        for (int i = 0; i < 4; ++i) {
            int r = r0 + tr + i * 16;
            float4 v = *(const float4*)(in + (long)r * C + c0 + tc * 4);
            tile[tr + i * 16][tc * 4 + 0] = v.x;
            tile[tr + i * 16][tc * 4 + 1] = v.y;
            tile[tr + i * 16][tc * 4 + 2] = v.z;
            tile[tr + i * 16][tc * 4 + 3] = v.w;
        }
    } else {
        #pragma unroll
        for (int i = 0; i < 4; ++i) {
            int r = r0 + tr + i * 16;
            #pragma unroll
            for (int e = 0; e < 4; ++e) {
                int c = c0 + tc * 4 + e;
                tile[tr + i * 16][tc * 4 + e] = (c < C) ? in[(long)r * C + c] : 0.f;
            }
        }
    }
    __syncthreads();
    #pragma unroll
    for (int p = 0; p < 2; ++p) {
        int n = (tid >> 3) + p * 32;
        int k0 = (tid & 7) * 8;
        if (c0 + n < C) {
            if (out8) {
                // weights scaled by 64 into e4m3 normal range; compensated in epilogues
                int2 w;
                w.x = pk4fp8(tile[k0 + 0][n] * 64.f, tile[k0 + 1][n] * 64.f,
                             tile[k0 + 2][n] * 64.f, tile[k0 + 3][n] * 64.f);
                w.y = pk4fp8(tile[k0 + 4][n] * 64.f, tile[k0 + 5][n] * 64.f,
                             tile[k0 + 6][n] * 64.f, tile[k0 + 7][n] * 64.f);
                *(int2*)(out8 + (long)(c0 + n) * R + r0 + k0) = w;
            } else {
                short8 o;
                #pragma unroll
                for (int j = 0; j < 8; ++j) o[j] = f2bf(tile[k0 + j][n]);
                *(short8*)(outb16 + (long)(c0 + n) * R + r0 + k0) = o;
            }
        }
    }
}

// ---------------- ROI-align v3 -> X fp8 [1024][12544] ----------
__global__ __launch_bounds__(256) void roi_align_v3(const short* __restrict__ featT,
                                                    const float* __restrict__ props,
                                                    unsigned char* __restrict__ Xb) {
    int roi = blockIdx.x;
    int img = roi >> 9;
    __shared__ unsigned int soffB[784];
    __shared__ float swB[784];
    __shared__ float pbox[4];
    __shared__ unsigned char outb[49 * 264];
    int tid = threadIdx.x;
    if (tid < 4) pbox[tid] = props[roi * 4 + tid];
    __syncthreads();
    if (tid < 196) {
        float x1 = pbox[0] * 0.0625f, y1 = pbox[1] * 0.0625f;
        float x2 = pbox[2] * 0.0625f, y2 = pbox[3] * 0.0625f;
        float rw = fmaxf(x2 - x1, 1.0f), rh = fmaxf(y2 - y1, 1.0f);
        int p = tid >> 2, q = tid & 3;
        int py = p / 7, px = p % 7;
        int sy = q >> 1, sx = q & 1;
        int gy = py * 2 + sy, gx = px * 2 + sx;
        float gyv = ((float)gy + 0.5f) * 0.5f;
        float gxv = ((float)gx + 0.5f) * 0.5f;
        float ys = y1 + gyv * (rh * (1.0f / 7.0f));
        float xs = x1 + gxv * (rw * (1.0f / 7.0f));
        ys = fminf(fmaxf(ys, 0.0f), 49.0f);
        xs = fminf(fmaxf(xs, 0.0f), 49.0f);
        float y0f = floorf(ys), x0f = floorf(xs);
        int y0 = (int)y0f, x0 = (int)x0f;
        int y1i = min(y0 + 1, 49), x1i = min(x0 + 1, 49);
        float ly = ys - y0f, lx = xs - x0f;
        float hy = 1.f - ly, hx = 1.f - lx;
        int b00 = (y0 * 50 + x0) << 9;
        int ddx = (x1i - x0) << 9;
        int ddy = (y1i - y0) * 25600;
        int t4 = tid << 2;
        soffB[t4 + 0] = b00;             swB[t4 + 0] = hy * hx * 0.25f;
        soffB[t4 + 1] = b00 + ddx;       swB[t4 + 1] = hy * lx * 0.25f;
        soffB[t4 + 2] = b00 + ddy;       swB[t4 + 2] = ly * hx * 0.25f;
        soffB[t4 + 3] = b00 + ddy + ddx; swB[t4 + 3] = ly * lx * 0.25f;
    }
    __syncthreads();
    int w = tid >> 6, l = tid & 63;
    int half = l >> 5, ch16 = l & 31;
    const char* fbase = (const char*)featT + (long)img * 1280000 + (ch16 << 4);
    for (int p = w; p < 49; p += 4) {
        float acc[8] = {};
        #pragma unroll
        for (int ld = 0; ld < 8; ++ld) {
            int idx = (p << 4) + (ld << 1) + half;
            unsigned int off = soffB[idx];
            float wgt = swB[idx];
            short8 v = *(const short8*)(fbase + off);
            union { short8 s; unsigned int u[4]; } uv;
            uv.s = v;
            #pragma unroll
            for (int k2 = 0; k2 < 4; ++k2) {
                unsigned int u = uv.u[k2];
                float flo = __uint_as_float(u << 16);
                float fhi = __uint_as_float(u & 0xffff0000u);
                acc[k2 * 2]     += wgt * flo;
                acc[k2 * 2 + 1] += wgt * fhi;
            }
        }
        float t[8];
        #pragma unroll
        for (int j = 0; j < 8; ++j) t[j] = acc[j] + __shfl_xor(acc[j], 32);
        if (half == 0) {
            int2 o;
            o.x = pk4fp8(t[0], t[1], t[2], t[3]);
            o.y = pk4fp8(t[4], t[5], t[6], t[7]);
            *(int2*)&outb[p * 264 + (ch16 << 3)] = o;
        }
    }
    __syncthreads();
    int c = tid / 49, r = tid % 49;
    unsigned char* xrow = Xb + (long)roi * 12544;
    #pragma unroll 1
    for (int i = 0; i < 49; ++i) {
        xrow[tid + i * 256] = outb[r * 264 + c];
        c += 5; r += 11;
        if (r >= 49) { r -= 49; c += 1; }
    }
}

// ---- fp8 MX MFMA 16x16x128 GEMM, 128x128 tile, BK=128B rows, dbuf + chunk-XOR swizzle.
// MODE 0: bf16 partials -> Cout + z*M*N (FC1 split-K; epilogue scale in reduce)
// MODE 1: fp8 out = relu(scale*acc + bias)  (FC2)
// MODE 2: f32 out = scale*acc + (bc|bb|0), stride/cols < Ncap  (head)
template <int MODE>
__global__ __launch_bounds__(256) void gemm128f8(const unsigned char* __restrict__ A,
                                                 const unsigned char* __restrict__ Bt,
                                                 const float* __restrict__ bias,
                                                 const float* __restrict__ bias2,
                                                 void* __restrict__ Cout,
                                                 int M, int N, int K, int kbase, int krem,
                                                 int Ncap, float scale) {
    __shared__ char As[2][16384];
    __shared__ char Bs[2][16384];
    int gx = gridDim.x, gy = gridDim.y;
    int nwg = gx * gy * gridDim.z;
    int orig = blockIdx.x + gx * (blockIdx.y + gy * blockIdx.z);
    int wg = orig;
    if ((nwg & 7) == 0 && nwg >= 64) {
        int q = nwg >> 3;
        wg = (orig & 7) * q + (orig >> 3);
    }
    int bx_ = wg % gx;
    int tmp = wg / gx;
    int by_ = tmp % gy;
    int bz_ = tmp / gy;
    int ksteps = kbase + (bz_ < krem ? 1 : 0);
    long kbeg = ((long)bz_ * kbase + (bz_ < krem ? bz_ : krem)) * 128;   // bytes = elems
    int m0 = by_ * 128, n0 = bx_ * 128;
    int tid = threadIdx.x;
    int w = tid >> 6, lane = tid & 63;
    int wr = w >> 1, wc = w & 1;
    int lr = lane & 15, lk = lane >> 4;
    int srow = tid >> 3;
    int sbx = ((tid & 7) ^ (srow & 7)) << 4;
    const unsigned char* Ag = A + (long)(m0 + srow) * K + kbeg + sbx;
    const unsigned char* Bg = Bt + (long)(n0 + srow) * K + kbeg + sbx;
    const long rstep = (long)K * 32;   // 32 rows per staging pass
    char* As0 = (char*)&As[0][0];
    char* Bs0 = (char*)&Bs[0][0];
    int wofs = w << 10;
    f32x4 acc[4][4] = {};

    #pragma unroll
    for (int i = 0; i < 4; ++i) {
        GLDS16(Ag + i * rstep, As0 + wofs + i * 4096);
        GLDS16(Bg + i * rstep, Bs0 + wofs + i * 4096);
    }
    __syncthreads();
    int cur = 0;
    const int sc1 = 0x7f7f7f7f;   // e8m0 = 127 -> scale 1.0 for all blocks
    for (int t = 0; t < ksteps; ++t) {
        if (t + 1 < ksteps) {   // issue next-tile stage BEFORE compute
            const unsigned char* a = Ag + (long)(t + 1) * 128;
            const unsigned char* b = Bg + (long)(t + 1) * 128;
            char* ad = As0 + ((cur ^ 1) << 14) + wofs;
            char* bd = Bs0 + ((cur ^ 1) << 14) + wofs;
            #pragma unroll
            for (int i = 0; i < 4; ++i) {
                GLDS16(a + i * rstep, ad + i * 4096);
                GLDS16(b + i * rstep, bd + i * 4096);
            }
        }
        const char* as = As0 + (cur << 14);
        const char* bs = Bs0 + (cur << 14);
        i32x8 av[4], bv[4];
        #pragma unroll
        for (int f = 0; f < 4; ++f) {
            int ra = wr * 64 + f * 16 + lr;
            int rb = wc * 64 + f * 16 + lr;
            int c0 = lk * 2;
            union { i32x8 v; f32x4 h[2]; } ua, ub;
            ua.h[0] = *(const f32x4*)(as + ra * 128 + (((c0 + 0) ^ (ra & 7)) << 4));
            ua.h[1] = *(const f32x4*)(as + ra * 128 + (((c0 + 1) ^ (ra & 7)) << 4));
            ub.h[0] = *(const f32x4*)(bs + rb * 128 + (((c0 + 0) ^ (rb & 7)) << 4));
            ub.h[1] = *(const f32x4*)(bs + rb * 128 + (((c0 + 1) ^ (rb & 7)) << 4));
            av[f] = ua.v; bv[f] = ub.v;
        }
        #pragma unroll
        for (int fm = 0; fm < 4; ++fm)
            #pragma unroll
            for (int fn = 0; fn < 4; ++fn)
                acc[fm][fn] = __builtin_amdgcn_mfma_scale_f32_16x16x128_f8f6f4(
                    av[fm], bv[fn], acc[fm][fn], 0, 0, 0, sc1, 0, sc1);
        __syncthreads();
        cur ^= 1;
    }
    #pragma unroll
    for (int fm = 0; fm < 4; ++fm) {
        #pragma unroll
        for (int fn = 0; fn < 4; ++fn) {
            int col = n0 + wc * 64 + fn * 16 + lr;
            float bv = 0.f;
            if (MODE == 1) bv = bias[col];
            if (MODE == 2) bv = (col < 81) ? bias[col] : (col < 405 ? bias2[col - 81] : 0.f);
            #pragma unroll
            for (int j = 0; j < 4; ++j) {
                int row = m0 + wr * 64 + fm * 16 + lk * 4 + j;
                float v = acc[fm][fn][j];
                if (MODE == 0) {
                    ((short*)Cout)[(long)bz_ * M * N + (long)row * N + col] = f2bf(v);
                } else if (MODE == 1) {
                    ((unsigned char*)Cout)[(long)row * N + col] =
                        f2fp8(fmaxf(fmaf(v, scale, bv), 0.f));
                } else {
                    if (col < Ncap)
                        ((float*)Cout)[(long)row * Ncap + col] = fmaf(v, scale, bv);
                }
            }
        }
    }
}

// --------- split-K reduce: H1 = relu(scale * sum_s P[s] + b1) -> fp8 ---------
__global__ void reduceN_relu(const short* __restrict__ P, const float* __restrict__ bias,
                             unsigned char* __restrict__ Hout, int nsl, float scale) {
    long i0 = ((long)blockIdx.x * 256 + threadIdx.x) * 8;
    int col = (int)(i0 & 1023);
    float v[8] = {};
    for (int s = 0; s < nsl; ++s) {
        short8 p = *(const short8*)(P + (long)s * 1048576 + i0);
        #pragma unroll
        for (int j = 0; j < 8; ++j) v[j] += bf2f(p[j]);
    }
    float h[8];
    #pragma unroll
    for (int j = 0; j < 8; ++j) h[j] = fmaxf(fmaf(v[j], scale, bias[col + j]), 0.f);
    int2 o;
    o.x = pk4fp8(h[0], h[1], h[2], h[3]);
    o.y = pk4fp8(h[4], h[5], h[6], h[7]);
    *(int2*)(Hout + i0) = o;
}

// ---------------- softmax + decode + valid ----------------
__global__ void head_epilogue(const float* __restrict__ O,      // [1024][448]
                              const float* __restrict__ props,
                              float* __restrict__ Boxes,
                              float* __restrict__ Scores,
                              unsigned char* __restrict__ Valid) {
    int roi = blockIdx.x;
    int lane = threadIdx.x;  // 64
    const float* o = O + (long)roi * 448;
    float m = -1e30f;
    for (int i = lane; i < 81; i += 64) m = fmaxf(m, o[i]);
    for (int off = 32; off > 0; off >>= 1) m = fmaxf(m, __shfl_xor(m, off));
    float ssum = 0.f;
    for (int i = lane; i < 81; i += 64) ssum += expf(o[i] - m);
    for (int off = 32; off > 0; off >>= 1) ssum += __shfl_xor(ssum, off);
    float inv = 1.0f / ssum;
    int img = roi >> 9, rb = roi & 511;
    float px1 = props[roi * 4 + 0], py1 = props[roi * 4 + 1];
    float px2 = props[roi * 4 + 2], py2 = props[roi * 4 + 3];
    float w = px2 - px1, h = py2 - py1;
    float cx = px1 + 0.5f * w, cy = py1 + 0.5f * h;
    long obase = (long)img * 40960 + (long)rb * 80;
    const float DW = 4.135166556742356f;
    for (int t = lane; t < 80; t += 64) {
        int cls = t + 1;
        float score = expf(o[cls] - m) * inv;
        const float* d = o + 81 + cls * 4;
        float dx = d[0] * 0.1f, dy = d[1] * 0.1f;
        float dw = fminf(d[2] * 0.2f, DW);
        float dh = fminf(d[3] * 0.2f, DW);
        float pcx = dx * w + cx, pcy = dy * h + cy;
        float pw = expf(dw) * w, ph = expf(dh) * h;
        float x1 = pcx - 0.5f * pw, y1 = pcy - 0.5f * ph;
        float x2 = pcx + 0.5f * pw, y2 = pcy + 0.5f * ph;
        x1 = fminf(fmaxf(x1, 0.f), 800.f); y1 = fminf(fmaxf(y1, 0.f), 800.f);
        x2 = fminf(fmaxf(x2, 0.f), 800.f); y2 = fminf(fmaxf(y2, 0.f), 800.f);
        float wv = x2 - x1, hv = y2 - y1;
        long oi = obase + t;
        Boxes[oi * 4 + 0] = x1; Boxes[oi * 4 + 1] = y1;
        Boxes[oi * 4 + 2] = x2; Boxes[oi * 4 + 3] = y2;
        Scores[oi] = score;
        Valid[oi] = (score >= 0.05f && wv >= 1.0f && hv >= 1.0f) ? 1 : 0;
    }
}

// ---------------- fused compaction + greedy NMS (one block per image) ----------------
__global__ void nms_fused(const float* __restrict__ Boxes, const float* __restrict__ Scores,
                          const unsigned char* __restrict__ Valid,
                          float* __restrict__ CB, int* __restrict__ CL,
                          float* __restrict__ CSw, float* __restrict__ out) {
    int img = blockIdx.x;
    int tid = threadIdx.x;  // 256
    const int SEG = 160;
    const unsigned char* V = Valid + (long)img * 40960;
    int j0 = tid * SEG;
    const unsigned int* V4 = (const unsigned int*)(V + j0);
    int c = 0;
    #pragma unroll
    for (int k = 0; k < 40; ++k) {
        unsigned int u = V4[k];
        c += (int)((u * 0x01010101u) >> 24);
    }
    __shared__ int cnt[256];
    cnt[tid] = c;
    __syncthreads();
    for (int d = 1; d < 256; d <<= 1) {
        int v = (tid >= d) ? cnt[tid - d] : 0;
        __syncthreads();
        cnt[tid] += v;
        __syncthreads();
    }
    int pos = cnt[tid] - c;
    const float* B = Boxes + (long)img * 40960 * 4;
    const float* S = Scores + (long)img * 40960;
    float* cb = CB + (long)img * 40960 * 4;
    float* sc = CSw + (long)img * 40960;
    int* cl = CL + (long)img * 40960;
    if (c > 0) {
        for (int k = 0; k < SEG; ++k) {
            int j = j0 + k;
            if (V[j]) {
                sc[pos] = S[j];
                cb[pos * 4 + 0] = B[j * 4 + 0]; cb[pos * 4 + 1] = B[j * 4 + 1];
                cb[pos * 4 + 2] = B[j * 4 + 2]; cb[pos * 4 + 3] = B[j * 4 + 3];
                cl[pos] = (j % 80) + 1;
                ++pos;
            }
        }
    }
    int Vn = cnt[255];
    for (int i = tid; i < 400; i += 256) out[img * 400 + i] = 0.f;
    if (tid < 100) {
        out[800 + img * 100 + tid] = 0.f;
        out[1000 + img * 100 + tid] = 0.f;
        out[1200 + img * 100 + tid] = 0.f;
    }
    __syncthreads();
    __shared__ float rv[256];
    __shared__ int ri[256];
    __shared__ float selbox[4];
    const float NEG = -__builtin_inff();
    for (int det = 0; det < 100; ++det) {
        float bv = NEG; int bi = -1;
        for (int j = tid; j < Vn; j += 256) {
            float s = sc[j];
            if (s > bv) { bv = s; bi = j; }
        }
        rv[tid] = bv; ri[tid] = bi;
        __syncthreads();
        for (int off = 128; off > 0; off >>= 1) {
            if (tid < off) {
                float ov = rv[tid + off]; int oi = ri[tid + off];
                if (ov > rv[tid] ||
                    (ov == rv[tid] && oi != -1 && (ri[tid] == -1 || oi < ri[tid]))) {
                    rv[tid] = ov; ri[tid] = oi;
                }
            }
            __syncthreads();
        }
        float mval = rv[0]; int mi = ri[0];
        if (!(mval > NEG) || mi < 0) break;
        if (tid == 0) {
            out[img * 400 + det * 4 + 0] = cb[mi * 4 + 0];
            out[img * 400 + det * 4 + 1] = cb[mi * 4 + 1];
            out[img * 400 + det * 4 + 2] = cb[mi * 4 + 2];
            out[img * 400 + det * 4 + 3] = cb[mi * 4 + 3];
            out[800 + img * 100 + det] = mval;
            out[1000 + img * 100 + det] = (float)cl[mi];
            out[1200 + img * 100 + det] = 1.0f;
            selbox[0] = cb[mi * 4 + 0]; selbox[1] = cb[mi * 4 + 1];
            selbox[2] = cb[mi * 4 + 2]; selbox[3] = cb[mi * 4 + 3];
            sc[mi] = NEG;
        }
        __syncthreads();
        float bx1 = selbox[0], by1 = selbox[1], bx2 = selbox[2], by2 = selbox[3];
        float a1 = (bx2 - bx1) * (by2 - by1);
        for (int j = tid; j < Vn; j += 256) {
            float s = sc[j];
            if (s == NEG) continue;
            float x1 = fmaxf(bx1, cb[j * 4 + 0]), y1 = fmaxf(by1, cb[j * 4 + 1]);
            float x2 = fminf(bx2, cb[j * 4 + 2]), y2 = fminf(by2, cb[j * 4 + 3]);
            float iw = fmaxf(x2 - x1, 0.f), ih = fmaxf(y2 - y1, 0.f);
            float inter = iw * ih;
            float a2 = (cb[j * 4 + 2] - cb[j * 4 + 0]) * (cb[j * 4 + 3] - cb[j * 4 + 1]);
            float iou = inter / (a1 + a2 - inter + 1e-9f);
            if (iou > 0.5f) sc[j] = NEG;
        }
        __syncthreads();
    }
}

extern "C" void kernel_launch(void* const* d_in, const int* in_sizes, int n_in,
                              void* d_out, int out_size, void* d_ws, size_t ws_size,
                              hipStream_t stream) {
    const float* features  = (const float*)d_in[0];
    const float* proposals = (const float*)d_in[1];
    const float* W1 = (const float*)d_in[2];
    const float* b1 = (const float*)d_in[3];
    const float* W2 = (const float*)d_in[4];
    const float* b2 = (const float*)d_in[5];
    const float* Wc = (const float*)d_in[6];
    const float* bc = (const float*)d_in[7];
    const float* Wb = (const float*)d_in[8];
    const float* bb = (const float*)d_in[9];

    // FC1 fp8 BK=128: 98 K-steps total. z=8 -> 512 blocks (2/CU).
    int zf1, kb1, kr1;
    if (ws_size >= 51380224UL + 8UL * 2097152UL + 2097152UL) { zf1 = 8; kb1 = 12; kr1 = 2; }
    else { zf1 = 4; kb1 = 24; kr1 = 2; }

    char* ws = (char*)d_ws;
    // phase A
    unsigned char* Xb  = (unsigned char*)(ws);             // [1024][12544] fp8, 12.8 MB
    unsigned char* W1t = (unsigned char*)(ws + 25690112);  // [1024][12544] fp8, 12.8 MB
    short* featT = (short*)(ws + 51380224);                // 2.56 MB (dead before P written)
    short* P     = (short*)(ws + 51380224);                // [zf1][1024][1024] bf16
    unsigned char* W2t8 = (unsigned char*)(ws + 51380224 + (size_t)zf1 * 2097152);  // 1 MB
    unsigned char* Wht8 = W2t8 + 1048576;                  // [512][1024] fp8, 0.5 MB
    // phase B (reuses ex-Xb region after FC1)
    unsigned char* H1b = (unsigned char*)(ws);             // 1 MB fp8
    unsigned char* H2b = (unsigned char*)(ws + 5242880);   // 1 MB fp8
    float* Obuf  = (float*)(ws + 7340032);                 // [1024][448] f32
    float* Boxes = (float*)(ws + 9175040);
    float* Scores= (float*)(ws + 10485760);
    unsigned char* Valid = (unsigned char*)(ws + 10813440);
    float* CB    = (float*)(ws + 10895360);
    int*   CL    = (int*)(ws + 12206080);
    float* CSw   = (float*)(ws + 12533760);

    transpose_v2<<<3840, 256, 0, stream>>>(W1, features, W2, Wc, Wb,
                                           W1t, featT, W2t8, Wht8);
    roi_align_v3<<<1024, 256, 0, stream>>>(featT, proposals, Xb);

    // FC1 fp8 (weights x64), z split-K -> bf16 partials -> H1 fp8 = relu(sum/64 + b1)
    gemm128f8<0><<<dim3(8, 8, zf1), 256, 0, stream>>>(Xb, W1t, nullptr, nullptr, (void*)P,
                                                      1024, 1024, 12544, kb1, kr1, 1024, 1.f);
    reduceN_relu<<<512, 256, 0, stream>>>(P, b1, H1b, zf1, 1.0f / 64.0f);

    // FC2 fp8 direct: H2 = relu(acc/64 + b2) -> fp8
    gemm128f8<1><<<dim3(8, 8, 1), 256, 0, stream>>>(H1b, W2t8, b2, nullptr, (void*)H2b,
                                                    1024, 1024, 1024, 8, 0, 1024, 1.0f / 64.0f);
    // head fp8 direct: Obuf = acc/64 + (bc|bb|0), f32, cols < 448
    gemm128f8<2><<<dim3(4, 8, 1), 256, 0, stream>>>(H2b, Wht8, bc, bb, (void*)Obuf,
                                                    1024, 512, 1024, 8, 0, 448, 1.0f / 64.0f);

    head_epilogue<<<1024, 64, 0, stream>>>(Obuf, proposals, Boxes, Scores, Valid);
    nms_fused<<<2, 256, 0, stream>>>(Boxes, Scores, Valid, CB, CL, CSw, (float*)d_out);
}

// Round 17
// 94.081 us; speedup vs baseline: 1.4039x; 1.0127x over previous
//
#include <hip/hip_runtime.h>
#include <hip/hip_bf16.h>

typedef __attribute__((ext_vector_type(8))) short short8;
typedef __attribute__((ext_vector_type(4))) float f32x4;
typedef __attribute__((ext_vector_type(2))) float f32x2;
typedef __attribute__((ext_vector_type(8))) int i32x8;

__device__ inline short f2bf(float x) {
    union { __hip_bfloat16 b; short s; } u;
    u.b = __float2bfloat16(x);
    return u.s;
}
__device__ inline float bf2f(short s) {
    union { __hip_bfloat16 b; short s; } u;
    u.s = s;
    return __bfloat162float(u.b);
}

#define GLDS16(g, l) __builtin_amdgcn_global_load_lds( \
    (const __attribute__((address_space(1))) void*)(g), \
    (__attribute__((address_space(3))) void*)(l), 16, 0, 0)

// pack 4 floats -> 4 fp8 e4m3 bytes (OCP on gfx950)
__device__ inline int pk4fp8(float a, float b, float c, float d) {
    int v = __builtin_amdgcn_cvt_pk_fp8_f32(a, b, 0, 0);
    v = __builtin_amdgcn_cvt_pk_fp8_f32(c, d, v, 1);
    return v;
}
__device__ inline unsigned char f2fp8(float a) {
    return (unsigned char)(__builtin_amdgcn_cvt_pk_fp8_f32(a, a, 0, 0) & 0xff);
}
// unpack 2 fp8 (low 2 bytes of word) -> 2 floats (native vector return type)
__device__ inline f32x2 upk2fp8(unsigned int w) {
    return __builtin_amdgcn_cvt_pk_f32_fp8(w, false);
}

// ------- transpose v2: 64x64 tiles; weights -> fp8(x64), features -> bf16 -------
// jobs: [0,3136) W1 | [3136,3456) features x2 | [3456,3712) W2 | [3712,3744) Wc
//       | [3744,3840) Wb
__global__ __launch_bounds__(256) void transpose_v2(const float* __restrict__ W1,
                                                    const float* __restrict__ features,
                                                    const float* __restrict__ W2,
                                                    const float* __restrict__ Wc,
                                                    const float* __restrict__ Wb,
                                                    unsigned char* __restrict__ W1t8,
                                                    short* __restrict__ featT,
                                                    unsigned char* __restrict__ W2t8,
                                                    unsigned char* __restrict__ Wht8) {
    __shared__ float tile[64][65];
    int id = blockIdx.x;
    const float* in;
    short* outb16 = nullptr;
    unsigned char* out8 = nullptr;
    int R, C, r0, c0;
    if (id < 3136) {
        in = W1; out8 = W1t8; R = 12544; C = 1024;
        r0 = (id % 196) * 64; c0 = (id / 196) * 64;
    } else if (id < 3456) {
        int f = id - 3136;
        int img = f / 160, g = f % 160;
        in = features + (long)img * 640000;
        outb16 = featT + (long)img * 640000;
        R = 256; C = 2500;
        r0 = (g % 4) * 64; c0 = (g / 4) * 64;
    } else if (id < 3712) {
        int g = id - 3456;
        in = W2; out8 = W2t8; R = 1024; C = 1024;
        r0 = (g % 16) * 64; c0 = (g / 16) * 64;
    } else if (id < 3744) {
        int g = id - 3712;
        in = Wc; out8 = Wht8; R = 1024; C = 81;
        r0 = (g % 16) * 64; c0 = (g / 16) * 64;
    } else {
        int g = id - 3744;
        in = Wb; out8 = Wht8 + 81 * 1024; R = 1024; C = 324;
        r0 = (g % 16) * 64; c0 = (g / 16) * 64;
    }
    int tid = threadIdx.x;
    int tr = tid >> 4, tc = tid & 15;
    if (c0 + 64 <= C) {
        #pragma unroll
        for (int i = 0; i < 4; ++i) {
            int r = r0 + tr + i * 16;
            float4 v = *(const float4*)(in + (long)r * C + c0 + tc * 4);
            tile[tr + i * 16][tc * 4 + 0] = v.x;
            tile[tr + i * 16][tc * 4 + 1] = v.y;
            tile[tr + i * 16][tc * 4 + 2] = v.z;
            tile[tr + i * 16][tc * 4 + 3] = v.w;
        }
    } else {
        #pragma unroll
        for (int i = 0; i < 4; ++i) {
            int r = r0 + tr + i * 16;
            #pragma unroll
            for (int e = 0; e < 4; ++e) {
                int c = c0 + tc * 4 + e;
                tile[tr + i * 16][tc * 4 + e] = (c < C) ? in[(long)r * C + c] : 0.f;
            }
        }
    }
    __syncthreads();
    #pragma unroll
    for (int p = 0; p < 2; ++p) {
        int n = (tid >> 3) + p * 32;
        int k0 = (tid & 7) * 8;
        if (c0 + n < C) {
            if (out8) {
                // weights scaled by 64 into e4m3 normal range; compensated in epilogues
                int2 w;
                w.x = pk4fp8(tile[k0 + 0][n] * 64.f, tile[k0 + 1][n] * 64.f,
                             tile[k0 + 2][n] * 64.f, tile[k0 + 3][n] * 64.f);
                w.y = pk4fp8(tile[k0 + 4][n] * 64.f, tile[k0 + 5][n] * 64.f,
                             tile[k0 + 6][n] * 64.f, tile[k0 + 7][n] * 64.f);
                *(int2*)(out8 + (long)(c0 + n) * R + r0 + k0) = w;
            } else {
                short8 o;
                #pragma unroll
                for (int j = 0; j < 8; ++j) o[j] = f2bf(tile[k0 + j][n]);
                *(short8*)(outb16 + (long)(c0 + n) * R + r0 + k0) = o;
            }
        }
    }
}

// ---------------- ROI-align v3 -> X fp8 [1024][12544] ----------
__global__ __launch_bounds__(256) void roi_align_v3(const short* __restrict__ featT,
                                                    const float* __restrict__ props,
                                                    unsigned char* __restrict__ Xb) {
    int roi = blockIdx.x;
    int img = roi >> 9;
    __shared__ unsigned int soffB[784];
    __shared__ float swB[784];
    __shared__ float pbox[4];
    __shared__ unsigned char outb[49 * 264];
    int tid = threadIdx.x;
    if (tid < 4) pbox[tid] = props[roi * 4 + tid];
    __syncthreads();
    if (tid < 196) {
        float x1 = pbox[0] * 0.0625f, y1 = pbox[1] * 0.0625f;
        float x2 = pbox[2] * 0.0625f, y2 = pbox[3] * 0.0625f;
        float rw = fmaxf(x2 - x1, 1.0f), rh = fmaxf(y2 - y1, 1.0f);
        int p = tid >> 2, q = tid & 3;
        int py = p / 7, px = p % 7;
        int sy = q >> 1, sx = q & 1;
        int gy = py * 2 + sy, gx = px * 2 + sx;
        float gyv = ((float)gy + 0.5f) * 0.5f;
        float gxv = ((float)gx + 0.5f) * 0.5f;
        float ys = y1 + gyv * (rh * (1.0f / 7.0f));
        float xs = x1 + gxv * (rw * (1.0f / 7.0f));
        ys = fminf(fmaxf(ys, 0.0f), 49.0f);
        xs = fminf(fmaxf(xs, 0.0f), 49.0f);
        float y0f = floorf(ys), x0f = floorf(xs);
        int y0 = (int)y0f, x0 = (int)x0f;
        int y1i = min(y0 + 1, 49), x1i = min(x0 + 1, 49);
        float ly = ys - y0f, lx = xs - x0f;
        float hy = 1.f - ly, hx = 1.f - lx;
        int b00 = (y0 * 50 + x0) << 9;
        int ddx = (x1i - x0) << 9;
        int ddy = (y1i - y0) * 25600;
        int t4 = tid << 2;
        soffB[t4 + 0] = b00;             swB[t4 + 0] = hy * hx * 0.25f;
        soffB[t4 + 1] = b00 + ddx;       swB[t4 + 1] = hy * lx * 0.25f;
        soffB[t4 + 2] = b00 + ddy;       swB[t4 + 2] = ly * hx * 0.25f;
        soffB[t4 + 3] = b00 + ddy + ddx; swB[t4 + 3] = ly * lx * 0.25f;
    }
    __syncthreads();
    int w = tid >> 6, l = tid & 63;
    int half = l >> 5, ch16 = l & 31;
    const char* fbase = (const char*)featT + (long)img * 1280000 + (ch16 << 4);
    for (int p = w; p < 49; p += 4) {
        float acc[8] = {};
        #pragma unroll
        for (int ld = 0; ld < 8; ++ld) {
            int idx = (p << 4) + (ld << 1) + half;
            unsigned int off = soffB[idx];
            float wgt = swB[idx];
            short8 v = *(const short8*)(fbase + off);
            union { short8 s; unsigned int u[4]; } uv;
            uv.s = v;
            #pragma unroll
            for (int k2 = 0; k2 < 4; ++k2) {
                unsigned int u = uv.u[k2];
                float flo = __uint_as_float(u << 16);
                float fhi = __uint_as_float(u & 0xffff0000u);
                acc[k2 * 2]     += wgt * flo;
                acc[k2 * 2 + 1] += wgt * fhi;
            }
        }
        float t[8];
        #pragma unroll
        for (int j = 0; j < 8; ++j) t[j] = acc[j] + __shfl_xor(acc[j], 32);
        if (half == 0) {
            int2 o;
            o.x = pk4fp8(t[0], t[1], t[2], t[3]);
            o.y = pk4fp8(t[4], t[5], t[6], t[7]);
            *(int2*)&outb[p * 264 + (ch16 << 3)] = o;
        }
    }
    __syncthreads();
    int c = tid / 49, r = tid % 49;
    unsigned char* xrow = Xb + (long)roi * 12544;
    #pragma unroll 1
    for (int i = 0; i < 49; ++i) {
        xrow[tid + i * 256] = outb[r * 264 + c];
        c += 5; r += 11;
        if (r >= 49) { r -= 49; c += 1; }
    }
}

// ---- fp8 MX MFMA 16x16x128 GEMM, 128x128 tile, BK=128B rows, dbuf + chunk-XOR swizzle.
// MODE 0: fp8 partials -> Cout + z*M*N (FC1 split-K; scale folded into reduce)
// MODE 1: fp8 out = relu(scale*acc + bias)  (FC2)
// MODE 2: f32 out = scale*acc + (bc|bb|0), stride/cols < Ncap  (head)
template <int MODE>
__global__ __launch_bounds__(256) void gemm128f8(const unsigned char* __restrict__ A,
                                                 const unsigned char* __restrict__ Bt,
                                                 const float* __restrict__ bias,
                                                 const float* __restrict__ bias2,
                                                 void* __restrict__ Cout,
                                                 int M, int N, int K, int kbase, int krem,
                                                 int Ncap, float scale) {
    __shared__ char As[2][16384];
    __shared__ char Bs[2][16384];
    int gx = gridDim.x, gy = gridDim.y;
    int nwg = gx * gy * gridDim.z;
    int orig = blockIdx.x + gx * (blockIdx.y + gy * blockIdx.z);
    int wg = orig;
    if ((nwg & 7) == 0 && nwg >= 64) {
        int q = nwg >> 3;
        wg = (orig & 7) * q + (orig >> 3);
    }
    int bx_ = wg % gx;
    int tmp = wg / gx;
    int by_ = tmp % gy;
    int bz_ = tmp / gy;
    int ksteps = kbase + (bz_ < krem ? 1 : 0);
    long kbeg = ((long)bz_ * kbase + (bz_ < krem ? bz_ : krem)) * 128;   // bytes = elems
    int m0 = by_ * 128, n0 = bx_ * 128;
    int tid = threadIdx.x;
    int w = tid >> 6, lane = tid & 63;
    int wr = w >> 1, wc = w & 1;
    int lr = lane & 15, lk = lane >> 4;
    int srow = tid >> 3;
    int sbx = ((tid & 7) ^ (srow & 7)) << 4;
    const unsigned char* Ag = A + (long)(m0 + srow) * K + kbeg + sbx;
    const unsigned char* Bg = Bt + (long)(n0 + srow) * K + kbeg + sbx;
    const long rstep = (long)K * 32;   // 32 rows per staging pass
    char* As0 = (char*)&As[0][0];
    char* Bs0 = (char*)&Bs[0][0];
    int wofs = w << 10;
    f32x4 acc[4][4] = {};

    #pragma unroll
    for (int i = 0; i < 4; ++i) {
        GLDS16(Ag + i * rstep, As0 + wofs + i * 4096);
        GLDS16(Bg + i * rstep, Bs0 + wofs + i * 4096);
    }
    __syncthreads();
    int cur = 0;
    const int sc1 = 0x7f7f7f7f;   // e8m0 = 127 -> scale 1.0 for all blocks
    for (int t = 0; t < ksteps; ++t) {
        if (t + 1 < ksteps) {   // issue next-tile stage BEFORE compute
            const unsigned char* a = Ag + (long)(t + 1) * 128;
            const unsigned char* b = Bg + (long)(t + 1) * 128;
            char* ad = As0 + ((cur ^ 1) << 14) + wofs;
            char* bd = Bs0 + ((cur ^ 1) << 14) + wofs;
            #pragma unroll
            for (int i = 0; i < 4; ++i) {
                GLDS16(a + i * rstep, ad + i * 4096);
                GLDS16(b + i * rstep, bd + i * 4096);
            }
        }
        const char* as = As0 + (cur << 14);
        const char* bs = Bs0 + (cur << 14);
        i32x8 av[4], bv[4];
        #pragma unroll
        for (int f = 0; f < 4; ++f) {
            int ra = wr * 64 + f * 16 + lr;
            int rb = wc * 64 + f * 16 + lr;
            int c0 = lk * 2;
            union { i32x8 v; f32x4 h[2]; } ua, ub;
            ua.h[0] = *(const f32x4*)(as + ra * 128 + (((c0 + 0) ^ (ra & 7)) << 4));
            ua.h[1] = *(const f32x4*)(as + ra * 128 + (((c0 + 1) ^ (ra & 7)) << 4));
            ub.h[0] = *(const f32x4*)(bs + rb * 128 + (((c0 + 0) ^ (rb & 7)) << 4));
            ub.h[1] = *(const f32x4*)(bs + rb * 128 + (((c0 + 1) ^ (rb & 7)) << 4));
            av[f] = ua.v; bv[f] = ub.v;
        }
        #pragma unroll
        for (int fm = 0; fm < 4; ++fm)
            #pragma unroll
            for (int fn = 0; fn < 4; ++fn)
                acc[fm][fn] = __builtin_amdgcn_mfma_scale_f32_16x16x128_f8f6f4(
                    av[fm], bv[fn], acc[fm][fn], 0, 0, 0, sc1, 0, sc1);
        __syncthreads();
        cur ^= 1;
    }
    #pragma unroll
    for (int fm = 0; fm < 4; ++fm) {
        #pragma unroll
        for (int fn = 0; fn < 4; ++fn) {
            int col = n0 + wc * 64 + fn * 16 + lr;
            float bv = 0.f;
            if (MODE == 1) bv = bias[col];
            if (MODE == 2) bv = (col < 81) ? bias[col] : (col < 405 ? bias2[col - 81] : 0.f);
            #pragma unroll
            for (int j = 0; j < 4; ++j) {
                int row = m0 + wr * 64 + fm * 16 + lk * 4 + j;
                float v = acc[fm][fn][j];
                if (MODE == 0) {
                    // fp8 partial (slice sums |.| < ~150, well inside e4m3 range 448)
                    ((unsigned char*)Cout)[(long)bz_ * M * N + (long)row * N + col] = f2fp8(v);
                } else if (MODE == 1) {
                    ((unsigned char*)Cout)[(long)row * N + col] =
                        f2fp8(fmaxf(fmaf(v, scale, bv), 0.f));
                } else {
                    if (col < Ncap)
                        ((float*)Cout)[(long)row * Ncap + col] = fmaf(v, scale, bv);
                }
            }
        }
    }
}

// --------- split-K reduce: H1 = relu(scale * sum_s P[s] + b1) -> fp8 (P is fp8) -------
__global__ void reduceN_relu(const unsigned char* __restrict__ P,
                             const float* __restrict__ bias,
                             unsigned char* __restrict__ Hout, int nsl, float scale) {
    long i0 = ((long)blockIdx.x * 256 + threadIdx.x) * 8;
    int col = (int)(i0 & 1023);
    float v[8] = {};
    for (int s = 0; s < nsl; ++s) {
        int2 p = *(const int2*)(P + (long)s * 1048576 + i0);
        unsigned int w0 = (unsigned int)p.x, w1 = (unsigned int)p.y;
        f32x2 a0 = upk2fp8(w0);
        f32x2 a1 = upk2fp8(w0 >> 16);
        f32x2 a2 = upk2fp8(w1);
        f32x2 a3 = upk2fp8(w1 >> 16);
        v[0] += a0[0]; v[1] += a0[1]; v[2] += a1[0]; v[3] += a1[1];
        v[4] += a2[0]; v[5] += a2[1]; v[6] += a3[0]; v[7] += a3[1];
    }
    float h[8];
    #pragma unroll
    for (int j = 0; j < 8; ++j) h[j] = fmaxf(fmaf(v[j], scale, bias[col + j]), 0.f);
    int2 o;
    o.x = pk4fp8(h[0], h[1], h[2], h[3]);
    o.y = pk4fp8(h[4], h[5], h[6], h[7]);
    *(int2*)(Hout + i0) = o;
}

// ---------------- softmax + decode + valid ----------------
__global__ void head_epilogue(const float* __restrict__ O,      // [1024][448]
                              const float* __restrict__ props,
                              float* __restrict__ Boxes,
                              float* __restrict__ Scores,
                              unsigned char* __restrict__ Valid) {
    int roi = blockIdx.x;
    int lane = threadIdx.x;  // 64
    const float* o = O + (long)roi * 448;
    float m = -1e30f;
    for (int i = lane; i < 81; i += 64) m = fmaxf(m, o[i]);
    for (int off = 32; off > 0; off >>= 1) m = fmaxf(m, __shfl_xor(m, off));
    float ssum = 0.f;
    for (int i = lane; i < 81; i += 64) ssum += expf(o[i] - m);
    for (int off = 32; off > 0; off >>= 1) ssum += __shfl_xor(ssum, off);
    float inv = 1.0f / ssum;
    int img = roi >> 9, rb = roi & 511;
    float px1 = props[roi * 4 + 0], py1 = props[roi * 4 + 1];
    float px2 = props[roi * 4 + 2], py2 = props[roi * 4 + 3];
    float w = px2 - px1, h = py2 - py1;
    float cx = px1 + 0.5f * w, cy = py1 + 0.5f * h;
    long obase = (long)img * 40960 + (long)rb * 80;
    const float DW = 4.135166556742356f;
    for (int t = lane; t < 80; t += 64) {
        int cls = t + 1;
        float score = expf(o[cls] - m) * inv;
        const float* d = o + 81 + cls * 4;
        float dx = d[0] * 0.1f, dy = d[1] * 0.1f;
        float dw = fminf(d[2] * 0.2f, DW);
        float dh = fminf(d[3] * 0.2f, DW);
        float pcx = dx * w + cx, pcy = dy * h + cy;
        float pw = expf(dw) * w, ph = expf(dh) * h;
        float x1 = pcx - 0.5f * pw, y1 = pcy - 0.5f * ph;
        float x2 = pcx + 0.5f * pw, y2 = pcy + 0.5f * ph;
        x1 = fminf(fmaxf(x1, 0.f), 800.f); y1 = fminf(fmaxf(y1, 0.f), 800.f);
        x2 = fminf(fmaxf(x2, 0.f), 800.f); y2 = fminf(fmaxf(y2, 0.f), 800.f);
        float wv = x2 - x1, hv = y2 - y1;
        long oi = obase + t;
        Boxes[oi * 4 + 0] = x1; Boxes[oi * 4 + 1] = y1;
        Boxes[oi * 4 + 2] = x2; Boxes[oi * 4 + 3] = y2;
        Scores[oi] = score;
        Valid[oi] = (score >= 0.05f && wv >= 1.0f && hv >= 1.0f) ? 1 : 0;
    }
}

// ---------------- fused compaction + greedy NMS (one block per image) ----------------
__global__ void nms_fused(const float* __restrict__ Boxes, const float* __restrict__ Scores,
                          const unsigned char* __restrict__ Valid,
                          float* __restrict__ CB, int* __restrict__ CL,
                          float* __restrict__ CSw, float* __restrict__ out) {
    int img = blockIdx.x;
    int tid = threadIdx.x;  // 256
    const int SEG = 160;
    const unsigned char* V = Valid + (long)img * 40960;
    int j0 = tid * SEG;
    const unsigned int* V4 = (const unsigned int*)(V + j0);
    int c = 0;
    #pragma unroll
    for (int k = 0; k < 40; ++k) {
        unsigned int u = V4[k];
        c += (int)((u * 0x01010101u) >> 24);
    }
    __shared__ int cnt[256];
    cnt[tid] = c;
    __syncthreads();
    for (int d = 1; d < 256; d <<= 1) {
        int v = (tid >= d) ? cnt[tid - d] : 0;
        __syncthreads();
        cnt[tid] += v;
        __syncthreads();
    }
    int pos = cnt[tid] - c;
    const float* B = Boxes + (long)img * 40960 * 4;
    const float* S = Scores + (long)img * 40960;
    float* cb = CB + (long)img * 40960 * 4;
    float* sc = CSw + (long)img * 40960;
    int* cl = CL + (long)img * 40960;
    if (c > 0) {
        for (int k = 0; k < SEG; ++k) {
            int j = j0 + k;
            if (V[j]) {
                sc[pos] = S[j];
                cb[pos * 4 + 0] = B[j * 4 + 0]; cb[pos * 4 + 1] = B[j * 4 + 1];
                cb[pos * 4 + 2] = B[j * 4 + 2]; cb[pos * 4 + 3] = B[j * 4 + 3];
                cl[pos] = (j % 80) + 1;
                ++pos;
            }
        }
    }
    int Vn = cnt[255];
    for (int i = tid; i < 400; i += 256) out[img * 400 + i] = 0.f;
    if (tid < 100) {
        out[800 + img * 100 + tid] = 0.f;
        out[1000 + img * 100 + tid] = 0.f;
        out[1200 + img * 100 + tid] = 0.f;
    }
    __syncthreads();
    __shared__ float rv[256];
    __shared__ int ri[256];
    __shared__ float selbox[4];
    const float NEG = -__builtin_inff();
    for (int det = 0; det < 100; ++det) {
        float bv = NEG; int bi = -1;
        for (int j = tid; j < Vn; j += 256) {
            float s = sc[j];
            if (s > bv) { bv = s; bi = j; }
        }
        rv[tid] = bv; ri[tid] = bi;
        __syncthreads();
        for (int off = 128; off > 0; off >>= 1) {
            if (tid < off) {
                float ov = rv[tid + off]; int oi = ri[tid + off];
                if (ov > rv[tid] ||
                    (ov == rv[tid] && oi != -1 && (ri[tid] == -1 || oi < ri[tid]))) {
                    rv[tid] = ov; ri[tid] = oi;
                }
            }
            __syncthreads();
        }
        float mval = rv[0]; int mi = ri[0];
        if (!(mval > NEG) || mi < 0) break;
        if (tid == 0) {
            out[img * 400 + det * 4 + 0] = cb[mi * 4 + 0];
            out[img * 400 + det * 4 + 1] = cb[mi * 4 + 1];
            out[img * 400 + det * 4 + 2] = cb[mi * 4 + 2];
            out[img * 400 + det * 4 + 3] = cb[mi * 4 + 3];
            out[800 + img * 100 + det] = mval;
            out[1000 + img * 100 + det] = (float)cl[mi];
            out[1200 + img * 100 + det] = 1.0f;
            selbox[0] = cb[mi * 4 + 0]; selbox[1] = cb[mi * 4 + 1];
            selbox[2] = cb[mi * 4 + 2]; selbox[3] = cb[mi * 4 + 3];
            sc[mi] = NEG;
        }
        __syncthreads();
        float bx1 = selbox[0], by1 = selbox[1], bx2 = selbox[2], by2 = selbox[3];
        float a1 = (bx2 - bx1) * (by2 - by1);
        for (int j = tid; j < Vn; j += 256) {
            float s = sc[j];
            if (s == NEG) continue;
            float x1 = fmaxf(bx1, cb[j * 4 + 0]), y1 = fmaxf(by1, cb[j * 4 + 1]);
            float x2 = fminf(bx2, cb[j * 4 + 2]), y2 = fminf(by2, cb[j * 4 + 3]);
            float iw = fmaxf(x2 - x1, 0.f), ih = fmaxf(y2 - y1, 0.f);
            float inter = iw * ih;
            float a2 = (cb[j * 4 + 2] - cb[j * 4 + 0]) * (cb[j * 4 + 3] - cb[j * 4 + 1]);
            float iou = inter / (a1 + a2 - inter + 1e-9f);
            if (iou > 0.5f) sc[j] = NEG;
        }
        __syncthreads();
    }
}

extern "C" void kernel_launch(void* const* d_in, const int* in_sizes, int n_in,
                              void* d_out, int out_size, void* d_ws, size_t ws_size,
                              hipStream_t stream) {
    const float* features  = (const float*)d_in[0];
    const float* proposals = (const float*)d_in[1];
    const float* W1 = (const float*)d_in[2];
    const float* b1 = (const float*)d_in[3];
    const float* W2 = (const float*)d_in[4];
    const float* b2 = (const float*)d_in[5];
    const float* Wc = (const float*)d_in[6];
    const float* bc = (const float*)d_in[7];
    const float* Wb = (const float*)d_in[8];
    const float* bb = (const float*)d_in[9];

    // FC1 fp8 BK=128: 98 K-steps total. z=8 -> 512 blocks (2/CU).
    int zf1, kb1, kr1;
    if (ws_size >= 51380224UL + 8UL * 1048576UL + 2097152UL) { zf1 = 8; kb1 = 12; kr1 = 2; }
    else { zf1 = 4; kb1 = 24; kr1 = 2; }

    char* ws = (char*)d_ws;
    // phase A
    unsigned char* Xb  = (unsigned char*)(ws);             // [1024][12544] fp8, 12.8 MB
    unsigned char* W1t = (unsigned char*)(ws + 25690112);  // [1024][12544] fp8, 12.8 MB
    short* featT = (short*)(ws + 51380224);                // 2.56 MB (dead before P written)
    unsigned char* P = (unsigned char*)(ws + 51380224);    // [zf1][1024][1024] fp8
    unsigned char* W2t8 = (unsigned char*)(ws + 51380224 + (size_t)zf1 * 1048576);  // 1 MB
    unsigned char* Wht8 = W2t8 + 1048576;                  // [512][1024] fp8, 0.5 MB
    // phase B (reuses ex-Xb region after FC1)
    unsigned char* H1b = (unsigned char*)(ws);             // 1 MB fp8
    unsigned char* H2b = (unsigned char*)(ws + 5242880);   // 1 MB fp8
    float* Obuf  = (float*)(ws + 7340032);                 // [1024][448] f32
    float* Boxes = (float*)(ws + 9175040);
    float* Scores= (float*)(ws + 10485760);
    unsigned char* Valid = (unsigned char*)(ws + 10813440);
    float* CB    = (float*)(ws + 10895360);
    int*   CL    = (int*)(ws + 12206080);
    float* CSw   = (float*)(ws + 12533760);

    transpose_v2<<<3840, 256, 0, stream>>>(W1, features, W2, Wc, Wb,
                                           W1t, featT, W2t8, Wht8);
    roi_align_v3<<<1024, 256, 0, stream>>>(featT, proposals, Xb);

    // FC1 fp8 (weights x64), z split-K -> fp8 partials -> H1 fp8 = relu(sum/64 + b1)
    gemm128f8<0><<<dim3(8, 8, zf1), 256, 0, stream>>>(Xb, W1t, nullptr, nullptr, (void*)P,
                                                      1024, 1024, 12544, kb1, kr1, 1024, 1.f);
    reduceN_relu<<<512, 256, 0, stream>>>(P, b1, H1b, zf1, 1.0f / 64.0f);

    // FC2 fp8 direct: H2 = relu(acc/64 + b2) -> fp8
    gemm128f8<1><<<dim3(8, 8, 1), 256, 0, stream>>>(H1b, W2t8, b2, nullptr, (void*)H2b,
                                                    1024, 1024, 1024, 8, 0, 1024, 1.0f / 64.0f);
    // head fp8 direct: Obuf = acc/64 + (bc|bb|0), f32, cols < 448
    gemm128f8<2><<<dim3(4, 8, 1), 256, 0, stream>>>(H2b, Wht8, bc, bb, (void*)Obuf,
                                                    1024, 512, 1024, 8, 0, 448, 1.0f / 64.0f);

    head_epilogue<<<1024, 64, 0, stream>>>(Obuf, proposals, Boxes, Scores, Valid);
    nms_fused<<<2, 256, 0, stream>>>(Boxes, Scores, Valid, CB, CL, CSw, (float*)d_out);
}